// Round 1
// baseline (917.095 us; speedup 1.0000x reference)
//
#include <hip/hip_runtime.h>

#define S_LEN 4096
#define DIMM  1024
#define NH    16
#define HD    64
#define HID   4096

typedef unsigned short u16;
typedef __attribute__((ext_vector_type(8))) short bf16x8;
typedef __attribute__((ext_vector_type(8))) unsigned short u16x8;
typedef __attribute__((ext_vector_type(4))) float f32x4;

__device__ __forceinline__ u16 f2bf(float f) {
  unsigned u = __float_as_uint(f);
  u += 0x7fffu + ((u >> 16) & 1u);   // round-to-nearest-even
  return (u16)(u >> 16);
}
__device__ __forceinline__ float bf2f(u16 h) {
  return __uint_as_float(((unsigned)h) << 16);
}

// ---------------- fp32 -> bf16 convert (8 elems/thread) ----------------
__global__ __launch_bounds__(256) void cvt_bf16_kernel(const float* __restrict__ in, u16* __restrict__ out) {
  int i = (blockIdx.x * 256 + threadIdx.x) * 8;
  float4 a = *(const float4*)(in + i);
  float4 b = *(const float4*)(in + i + 4);
  u16x8 r;
  r[0] = f2bf(a.x); r[1] = f2bf(a.y); r[2] = f2bf(a.z); r[3] = f2bf(a.w);
  r[4] = f2bf(b.x); r[5] = f2bf(b.y); r[6] = f2bf(b.z); r[7] = f2bf(b.w);
  *(u16x8*)(out + i) = r;
}

// ---------------- RMSNorm: fp32 in -> bf16 out ----------------
__global__ __launch_bounds__(256) void rmsnorm_kernel(const float* __restrict__ x, const float* __restrict__ g,
                                                      u16* __restrict__ out) {
  int row = blockIdx.x;
  int t = threadIdx.x;
  const float4 v = *(const float4*)(x + (size_t)row * DIMM + t * 4);
  float ss = v.x * v.x + v.y * v.y + v.z * v.z + v.w * v.w;
#pragma unroll
  for (int off = 32; off > 0; off >>= 1) ss += __shfl_down(ss, off);
  __shared__ float red[4];
  if ((t & 63) == 0) red[t >> 6] = ss;
  __syncthreads();
  float tot = red[0] + red[1] + red[2] + red[3];
  float sc = rsqrtf(tot * (1.0f / DIMM) + 1e-6f);
  const float4 gv = *(const float4*)(g + t * 4);
  ushort4 o;
  o.x = f2bf(v.x * sc * gv.x);
  o.y = f2bf(v.y * sc * gv.y);
  o.z = f2bf(v.z * sc * gv.z);
  o.w = f2bf(v.w * sc * gv.w);
  *(ushort4*)(out + (size_t)row * DIMM + t * 4) = o;
}

// ---------------- bf16 MFMA GEMM: C[M,N] = A[M,K] * B[N,K]^T ----------------
// 128x128 tile, BK=32, 4 waves 2x2, fragment-contiguous LDS (conflict-free).
// OUTMODE 0: store bf16. OUTMODE 1: store fp32 = res + acc.
template <int OUTMODE>
__global__ __launch_bounds__(256) void gemm_kernel(const u16* __restrict__ A, const u16* __restrict__ B,
                                                   void* Cout, const float* res, int N, int K) {
  __shared__ uint4 As[512];
  __shared__ uint4 Bs[512];
  const int t = threadIdx.x;
  const int w = t >> 6, l = t & 63;
  const int bm = blockIdx.y, bn = blockIdx.x;
  const int quad = l >> 4, lc = l & 15;

  f32x4 acc[4][4];
  const f32x4 zero = {0.0f, 0.0f, 0.0f, 0.0f};
#pragma unroll
  for (int mi = 0; mi < 4; mi++)
#pragma unroll
    for (int ni = 0; ni < 4; ni++) acc[mi][ni] = zero;

  const int id0 = t, id1 = t + 256;
  const int band0 = id0 >> 6, kq0 = (id0 >> 4) & 3, row0 = id0 & 15;
  const int band1 = id1 >> 6, kq1 = (id1 >> 4) & 3, row1 = id1 & 15;
  const u16* Ap0 = A + (size_t)(bm * 128 + band0 * 16 + row0) * K + kq0 * 8;
  const u16* Ap1 = A + (size_t)(bm * 128 + band1 * 16 + row1) * K + kq1 * 8;
  const u16* Bp0 = B + (size_t)(bn * 128 + band0 * 16 + row0) * K + kq0 * 8;
  const u16* Bp1 = B + (size_t)(bn * 128 + band1 * 16 + row1) * K + kq1 * 8;
  const int abase = (w >> 1) * 256 + l;
  const int bbase = (w & 1) * 256 + l;

  for (int k0 = 0; k0 < K; k0 += 32) {
    As[id0] = *(const uint4*)(Ap0 + k0);
    As[id1] = *(const uint4*)(Ap1 + k0);
    Bs[id0] = *(const uint4*)(Bp0 + k0);
    Bs[id1] = *(const uint4*)(Bp1 + k0);
    __syncthreads();
    bf16x8 af[4], bfr[4];
#pragma unroll
    for (int mi = 0; mi < 4; mi++) af[mi] = *(const bf16x8*)&As[abase + mi * 64];
#pragma unroll
    for (int ni = 0; ni < 4; ni++) bfr[ni] = *(const bf16x8*)&Bs[bbase + ni * 64];
#pragma unroll
    for (int mi = 0; mi < 4; mi++)
#pragma unroll
      for (int ni = 0; ni < 4; ni++)
        acc[mi][ni] = __builtin_amdgcn_mfma_f32_16x16x32_bf16(af[mi], bfr[ni], acc[mi][ni], 0, 0, 0);
    __syncthreads();
  }

  const int rbase = bm * 128 + (w >> 1) * 64 + quad * 4;
  const int cbase = bn * 128 + (w & 1) * 64 + lc;
#pragma unroll
  for (int mi = 0; mi < 4; mi++) {
#pragma unroll
    for (int r = 0; r < 4; r++) {
      int row = rbase + mi * 16 + r;
#pragma unroll
      for (int ni = 0; ni < 4; ni++) {
        int col = cbase + ni * 16;
        size_t idx = (size_t)row * N + col;
        if constexpr (OUTMODE == 0) {
          ((u16*)Cout)[idx] = f2bf(acc[mi][ni][r]);
        } else {
          ((float*)Cout)[idx] = res[idx] + acc[mi][ni][r];
        }
      }
    }
  }
}

// ---------------- RoPE tables (fp64 for phase accuracy) ----------------
__global__ __launch_bounds__(256) void rope_tables_kernel(float* __restrict__ cosT, float* __restrict__ sinT) {
  int idx = blockIdx.x * 256 + threadIdx.x;  // 4096*32
  int pos = idx >> 5, i = idx & 31;
  double inv = pow(10000.0, -(double)(2 * i) / 64.0);
  double a = (double)pos * inv;
  cosT[idx] = (float)cos(a);
  sinT[idx] = (float)sin(a);
}

__global__ __launch_bounds__(256) void rope_apply_kernel(u16* __restrict__ q, u16* __restrict__ k,
                                                         const float* __restrict__ cosT,
                                                         const float* __restrict__ sinT) {
  int idx = blockIdx.x * 256 + threadIdx.x;  // 4096*16*32
  int pos = idx >> 9, h = (idx >> 5) & 15, i = idx & 31;
  float c = cosT[(pos << 5) + i], s = sinT[(pos << 5) + i];
  size_t base = (size_t)pos * DIMM + h * HD + 2 * i;
  float re = bf2f(q[base]), im = bf2f(q[base + 1]);
  q[base] = f2bf(re * c - im * s);
  q[base + 1] = f2bf(re * s + im * c);
  re = bf2f(k[base]);
  im = bf2f(k[base + 1]);
  k[base] = f2bf(re * c - im * s);
  k[base + 1] = f2bf(re * s + im * c);
}

// ---------------- Flash attention (bf16 MFMA, online softmax) ----------------
// grid (64 q-tiles, 16 heads), 256 threads; wave w owns 16 Q rows.
__global__ __launch_bounds__(256) void attn_kernel(const u16* __restrict__ Q, const u16* __restrict__ Km,
                                                   const u16* __restrict__ Vm, u16* __restrict__ Om) {
  __shared__ uint4 Ks[512];      // K tile 64x64, fragment-contiguous
  __shared__ uint4 Vt[512];      // V tile transposed [dim][key], fragment-contiguous
  __shared__ uint4 Ps[4][128];   // per-wave P tile 16x64 in A-frag layout
  const int t = threadIdx.x;
  const int w = t >> 6, l = t & 63;
  const int quad = l >> 4, lc = l & 15;
  const int hd = blockIdx.y;
  const int qbase = blockIdx.x * 64;

  bf16x8 aq[2];
  {
    const u16* qp = Q + (size_t)(qbase + w * 16 + lc) * DIMM + hd * HD + quad * 8;
    aq[0] = *(const bf16x8*)qp;
    aq[1] = *(const bf16x8*)(qp + 32);
  }
  const f32x4 zero = {0.0f, 0.0f, 0.0f, 0.0f};
  f32x4 Oa[4];
#pragma unroll
  for (int d = 0; d < 4; d++) Oa[d] = zero;
  float m_r[4], l_r[4];
#pragma unroll
  for (int r = 0; r < 4; r++) { m_r[r] = -1e30f; l_r[r] = 0.0f; }

  for (int kt = 0; kt < S_LEN; kt += 64) {
    // stage K tile (fragment-contiguous: off16 = s*128 + c*64 + kq*16 + row)
#pragma unroll
    for (int i = 0; i < 2; i++) {
      int id = t + i * 256;
      int s = id >> 7, c = (id >> 6) & 1, kq = (id >> 4) & 3, row = id & 15;
      Ks[id] = *(const uint4*)(Km + (size_t)(kt + s * 16 + row) * DIMM + hd * HD + c * 32 + kq * 8);
    }
    // stage V transposed: Vt frag (td, c): lane lc=dim, keys c*32+quad*8+j
#pragma unroll
    for (int i = 0; i < 2; i++) {
      int id = t + i * 256;
      int kl = id >> 3, dq = id & 7;
      uint4 vv = *(const uint4*)(Vm + (size_t)(kt + kl) * DIMM + hd * HD + dq * 8);
      const u16* pv = (const u16*)&vv;
      u16* vtb = (u16*)Vt;
#pragma unroll
      for (int j = 0; j < 8; j++) {
        int d = dq * 8 + j;
        int off16 = (d >> 4) * 128 + (kl >> 5) * 64 + ((kl >> 3) & 3) * 16 + (d & 15);
        vtb[off16 * 8 + (kl & 7)] = pv[j];
      }
    }
    __syncthreads();

    // S = Q K^T / 8
    f32x4 Sf[4];
#pragma unroll
    for (int s = 0; s < 4; s++) {
      f32x4 z = zero;
      bf16x8 b0 = *(const bf16x8*)&Ks[s * 128 + l];
      bf16x8 b1 = *(const bf16x8*)&Ks[s * 128 + 64 + l];
      z = __builtin_amdgcn_mfma_f32_16x16x32_bf16(aq[0], b0, z, 0, 0, 0);
      z = __builtin_amdgcn_mfma_f32_16x16x32_bf16(aq[1], b1, z, 0, 0, 0);
      Sf[s] = z * 0.125f;
    }

    // online softmax (row stats over 16-lane groups sharing quad)
    float mn[4], alpha[4], rs[4];
#pragma unroll
    for (int r = 0; r < 4; r++) {
      float mx = fmaxf(fmaxf(Sf[0][r], Sf[1][r]), fmaxf(Sf[2][r], Sf[3][r]));
#pragma unroll
      for (int off = 1; off < 16; off <<= 1) mx = fmaxf(mx, __shfl_xor(mx, off));
      mn[r] = fmaxf(m_r[r], mx);
      alpha[r] = __expf(m_r[r] - mn[r]);
      m_r[r] = mn[r];
      rs[r] = 0.0f;
    }
#pragma unroll
    for (int s = 0; s < 4; s++)
#pragma unroll
      for (int r = 0; r < 4; r++) {
        float p = __expf(Sf[s][r] - mn[r]);
        Sf[s][r] = p;
        rs[r] += p;
      }
#pragma unroll
    for (int r = 0; r < 4; r++) {
#pragma unroll
      for (int off = 1; off < 16; off <<= 1) rs[r] += __shfl_xor(rs[r], off);
      l_r[r] = l_r[r] * alpha[r] + rs[r];
    }
#pragma unroll
    for (int d = 0; d < 4; d++)
#pragma unroll
      for (int r = 0; r < 4; r++) Oa[d][r] *= alpha[r];

    // write P (C-layout) into per-wave LDS in A-frag layout
    {
      u16* pw = (u16*)Ps[w];
#pragma unroll
      for (int s = 0; s < 4; s++) {
        int kcol = s * 16 + lc;
        int base16 = (kcol >> 5) * 64 + ((kcol >> 3) & 3) * 16;
#pragma unroll
        for (int r = 0; r < 4; r++) {
          pw[(base16 + quad * 4 + r) * 8 + (kcol & 7)] = f2bf(Sf[s][r]);
        }
      }
    }
    // PV (per-wave DS in-order: P writes complete before these reads)
#pragma unroll
    for (int c = 0; c < 2; c++) {
      bf16x8 ap = *(const bf16x8*)&Ps[w][c * 64 + l];
#pragma unroll
      for (int d = 0; d < 4; d++) {
        bf16x8 bv = *(const bf16x8*)&Vt[d * 128 + c * 64 + l];
        Oa[d] = __builtin_amdgcn_mfma_f32_16x16x32_bf16(ap, bv, Oa[d], 0, 0, 0);
      }
    }
    __syncthreads();
  }

  // normalize + store
#pragma unroll
  for (int r = 0; r < 4; r++) {
    float inv = 1.0f / l_r[r];
    int row = qbase + w * 16 + quad * 4 + r;
#pragma unroll
    for (int d = 0; d < 4; d++) {
      Om[(size_t)row * DIMM + hd * HD + d * 16 + lc] = f2bf(Oa[d][r] * inv);
    }
  }
}

// ---------------- silu(u) * g elementwise (bf16, in-place into u) ----------------
__global__ __launch_bounds__(256) void silu_mul_kernel(u16* __restrict__ u, const u16* __restrict__ g) {
  int i = (blockIdx.x * 256 + threadIdx.x) * 8;
  u16x8 uv = *(const u16x8*)(u + i);
  u16x8 gv = *(const u16x8*)(g + i);
  u16x8 r;
#pragma unroll
  for (int j = 0; j < 8; j++) {
    float a = bf2f(uv[j]);
    float b = bf2f(gv[j]);
    float sv = a / (1.0f + __expf(-a));
    r[j] = f2bf(sv * b);
  }
  *(u16x8*)(u + i) = r;
}

extern "C" void kernel_launch(void* const* d_in, const int* in_sizes, int n_in,
                              void* d_out, int out_size, void* d_ws, size_t ws_size,
                              hipStream_t stream) {
  const float* x      = (const float*)d_in[0];
  const float* wq     = (const float*)d_in[1];
  const float* wk     = (const float*)d_in[2];
  const float* wv     = (const float*)d_in[3];
  const float* wo     = (const float*)d_in[4];
  const float* w1     = (const float*)d_in[5];
  const float* w2     = (const float*)d_in[6];
  const float* w3     = (const float*)d_in[7];
  const float* g_attn = (const float*)d_in[8];
  const float* g_ffn  = (const float*)d_in[9];
  float* out = (float*)d_out;
  char* ws = (char*)d_ws;
  const size_t MB = 1ull << 20;

  u16* wqb  = (u16*)(ws + 0 * MB);
  u16* wkb  = (u16*)(ws + 2 * MB);
  u16* wvb  = (u16*)(ws + 4 * MB);
  u16* wob  = (u16*)(ws + 6 * MB);
  u16* w1b  = (u16*)(ws + 8 * MB);
  u16* w3b  = (u16*)(ws + 16 * MB);
  u16* w2b  = (u16*)(ws + 24 * MB);
  u16* xnb  = (u16*)(ws + 32 * MB);  // xn, later hn
  u16* qb   = (u16*)(ws + 40 * MB);
  u16* kb   = (u16*)(ws + 48 * MB);
  u16* vb   = (u16*)(ws + 56 * MB);
  u16* attb = (u16*)(ws + 64 * MB);
  u16* ub   = (u16*)(ws + 40 * MB);  // reuses q/k/v/att region after o-proj
  u16* gb   = (u16*)(ws + 72 * MB);
  float* cosT = (float*)(ws + 104 * MB);
  float* sinT = (float*)(ws + 104 * MB + 512 * 1024);

  // weights -> bf16
  cvt_bf16_kernel<<<512, 256, 0, stream>>>(wq, wqb);
  cvt_bf16_kernel<<<512, 256, 0, stream>>>(wk, wkb);
  cvt_bf16_kernel<<<512, 256, 0, stream>>>(wv, wvb);
  cvt_bf16_kernel<<<512, 256, 0, stream>>>(wo, wob);
  cvt_bf16_kernel<<<2048, 256, 0, stream>>>(w1, w1b);
  cvt_bf16_kernel<<<2048, 256, 0, stream>>>(w3, w3b);
  cvt_bf16_kernel<<<2048, 256, 0, stream>>>(w2, w2b);
  rope_tables_kernel<<<512, 256, 0, stream>>>(cosT, sinT);

  rmsnorm_kernel<<<4096, 256, 0, stream>>>(x, g_attn, xnb);

  dim3 g1(8, 32);   // N=1024 tiles x M=4096 tiles
  gemm_kernel<0><<<g1, 256, 0, stream>>>(xnb, wqb, qb, nullptr, DIMM, DIMM);
  gemm_kernel<0><<<g1, 256, 0, stream>>>(xnb, wkb, kb, nullptr, DIMM, DIMM);
  gemm_kernel<0><<<g1, 256, 0, stream>>>(xnb, wvb, vb, nullptr, DIMM, DIMM);

  rope_apply_kernel<<<8192, 256, 0, stream>>>(qb, kb, cosT, sinT);

  attn_kernel<<<dim3(64, 16), 256, 0, stream>>>(qb, kb, vb, attb);

  // h = x + attn @ wo^T  (h lives in d_out)
  gemm_kernel<1><<<g1, 256, 0, stream>>>(attb, wob, out, x, DIMM, DIMM);

  rmsnorm_kernel<<<4096, 256, 0, stream>>>(out, g_ffn, xnb);

  dim3 g2(32, 32);  // N=4096 tiles x M=4096 tiles
  gemm_kernel<0><<<g2, 256, 0, stream>>>(xnb, w1b, ub, nullptr, HID, DIMM);
  gemm_kernel<0><<<g2, 256, 0, stream>>>(xnb, w3b, gb, nullptr, HID, DIMM);

  silu_mul_kernel<<<8192, 256, 0, stream>>>(ub, gb);

  // out = h + ff @ w2^T  (in-place residual from d_out)
  gemm_kernel<1><<<g1, 256, 0, stream>>>(ub, w2b, out, out, DIMM, HID);
}

// Round 2
// 823.573 us; speedup vs baseline: 1.1136x; 1.1136x over previous
//
#include <hip/hip_runtime.h>

#define S_LEN 4096
#define DIMM  1024
#define NH    16
#define HD    64
#define HID   4096

typedef unsigned short u16;
typedef __attribute__((ext_vector_type(8))) short bf16x8;
typedef __attribute__((ext_vector_type(8))) unsigned short u16x8;
typedef __attribute__((ext_vector_type(4))) float f32x4;

__device__ __forceinline__ u16 f2bf(float f) {
  unsigned u = __float_as_uint(f);
  u += 0x7fffu + ((u >> 16) & 1u);   // round-to-nearest-even
  return (u16)(u >> 16);
}
__device__ __forceinline__ float bf2f(u16 h) {
  return __uint_as_float(((unsigned)h) << 16);
}

// async global->LDS, 16B per lane (dest must be wave-uniform base + lane*16)
__device__ __forceinline__ void gl_lds16(const void* g, void* l) {
  __builtin_amdgcn_global_load_lds(
      (const __attribute__((address_space(1))) void*)g,
      (__attribute__((address_space(3))) void*)l, 16, 0, 0);
}

// ---------------- fp32 -> bf16 convert (8 elems/thread) ----------------
__global__ __launch_bounds__(256) void cvt_bf16_kernel(const float* __restrict__ in, u16* __restrict__ out) {
  int i = (blockIdx.x * 256 + threadIdx.x) * 8;
  float4 a = *(const float4*)(in + i);
  float4 b = *(const float4*)(in + i + 4);
  u16x8 r;
  r[0] = f2bf(a.x); r[1] = f2bf(a.y); r[2] = f2bf(a.z); r[3] = f2bf(a.w);
  r[4] = f2bf(b.x); r[5] = f2bf(b.y); r[6] = f2bf(b.z); r[7] = f2bf(b.w);
  *(u16x8*)(out + i) = r;
}

// ---------------- RMSNorm: fp32 in -> bf16 out ----------------
__global__ __launch_bounds__(256) void rmsnorm_kernel(const float* __restrict__ x, const float* __restrict__ g,
                                                      u16* __restrict__ out) {
  int row = blockIdx.x;
  int t = threadIdx.x;
  const float4 v = *(const float4*)(x + (size_t)row * DIMM + t * 4);
  float ss = v.x * v.x + v.y * v.y + v.z * v.z + v.w * v.w;
#pragma unroll
  for (int off = 32; off > 0; off >>= 1) ss += __shfl_down(ss, off);
  __shared__ float red[4];
  if ((t & 63) == 0) red[t >> 6] = ss;
  __syncthreads();
  float tot = red[0] + red[1] + red[2] + red[3];
  float sc = rsqrtf(tot * (1.0f / DIMM) + 1e-6f);
  const float4 gv = *(const float4*)(g + t * 4);
  ushort4 o;
  o.x = f2bf(v.x * sc * gv.x);
  o.y = f2bf(v.y * sc * gv.y);
  o.z = f2bf(v.z * sc * gv.z);
  o.w = f2bf(v.w * sc * gv.w);
  *(ushort4*)(out + (size_t)row * DIMM + t * 4) = o;
}

// ---------------- bf16 MFMA GEMM: C[M,N] = A[M,K] * B[N,K]^T ----------------
// 128x128 tile, BK=32, 4 waves 2x2, fragment-contiguous LDS, global_load_lds staging.
// OUTMODE 0: store bf16. OUTMODE 1: store fp32 = res + acc.
template <int OUTMODE>
__global__ __launch_bounds__(256) void gemm_kernel(const u16* __restrict__ A, const u16* __restrict__ B,
                                                   void* Cout, const float* res, int N, int K) {
  __shared__ uint4 As[512];
  __shared__ uint4 Bs[512];
  const int t = threadIdx.x;
  const int w = t >> 6, l = t & 63;
  const int bm = blockIdx.y, bn = blockIdx.x;
  const int quad = l >> 4, lc = l & 15;

  f32x4 acc[4][4];
  const f32x4 zero = {0.0f, 0.0f, 0.0f, 0.0f};
#pragma unroll
  for (int mi = 0; mi < 4; mi++)
#pragma unroll
    for (int ni = 0; ni < 4; ni++) acc[mi][ni] = zero;

  const int id0 = t, id1 = t + 256;
  const int band0 = id0 >> 6, kq0 = (id0 >> 4) & 3, row0 = id0 & 15;
  const int band1 = id1 >> 6, kq1 = (id1 >> 4) & 3, row1 = id1 & 15;
  const u16* Ap0 = A + (size_t)(bm * 128 + band0 * 16 + row0) * K + kq0 * 8;
  const u16* Ap1 = A + (size_t)(bm * 128 + band1 * 16 + row1) * K + kq1 * 8;
  const u16* Bp0 = B + (size_t)(bn * 128 + band0 * 16 + row0) * K + kq0 * 8;
  const u16* Bp1 = B + (size_t)(bn * 128 + band1 * 16 + row1) * K + kq1 * 8;
  const int abase = (w >> 1) * 256 + l;
  const int bbase = (w & 1) * 256 + l;

  for (int k0 = 0; k0 < K; k0 += 32) {
    gl_lds16(Ap0 + k0, &As[id0]);
    gl_lds16(Ap1 + k0, &As[id1]);
    gl_lds16(Bp0 + k0, &Bs[id0]);
    gl_lds16(Bp1 + k0, &Bs[id1]);
    __syncthreads();
    bf16x8 af[4], bfr[4];
#pragma unroll
    for (int mi = 0; mi < 4; mi++) af[mi] = *(const bf16x8*)&As[abase + mi * 64];
#pragma unroll
    for (int ni = 0; ni < 4; ni++) bfr[ni] = *(const bf16x8*)&Bs[bbase + ni * 64];
#pragma unroll
    for (int mi = 0; mi < 4; mi++)
#pragma unroll
      for (int ni = 0; ni < 4; ni++)
        acc[mi][ni] = __builtin_amdgcn_mfma_f32_16x16x32_bf16(af[mi], bfr[ni], acc[mi][ni], 0, 0, 0);
    __syncthreads();
  }

  const int rbase = bm * 128 + (w >> 1) * 64 + quad * 4;
  const int cbase = bn * 128 + (w & 1) * 64 + lc;
#pragma unroll
  for (int mi = 0; mi < 4; mi++) {
#pragma unroll
    for (int r = 0; r < 4; r++) {
      int row = rbase + mi * 16 + r;
#pragma unroll
      for (int ni = 0; ni < 4; ni++) {
        int col = cbase + ni * 16;
        size_t idx = (size_t)row * N + col;
        if constexpr (OUTMODE == 0) {
          ((u16*)Cout)[idx] = f2bf(acc[mi][ni][r]);
        } else {
          ((float*)Cout)[idx] = res[idx] + acc[mi][ni][r];
        }
      }
    }
  }
}

// ---------------- RoPE tables (fp64 for phase accuracy) ----------------
__global__ __launch_bounds__(256) void rope_tables_kernel(float* __restrict__ cosT, float* __restrict__ sinT) {
  int idx = blockIdx.x * 256 + threadIdx.x;  // 4096*32
  int pos = idx >> 5, i = idx & 31;
  double inv = pow(10000.0, -(double)(2 * i) / 64.0);
  double a = (double)pos * inv;
  cosT[idx] = (float)cos(a);
  sinT[idx] = (float)sin(a);
}

__global__ __launch_bounds__(256) void rope_apply_kernel(u16* __restrict__ q, u16* __restrict__ k,
                                                         const float* __restrict__ cosT,
                                                         const float* __restrict__ sinT) {
  int idx = blockIdx.x * 256 + threadIdx.x;  // 4096*16*32
  int pos = idx >> 9, h = (idx >> 5) & 15, i = idx & 31;
  float c = cosT[(pos << 5) + i], s = sinT[(pos << 5) + i];
  size_t base = (size_t)pos * DIMM + h * HD + 2 * i;
  float re = bf2f(q[base]), im = bf2f(q[base + 1]);
  q[base] = f2bf(re * c - im * s);
  q[base + 1] = f2bf(re * s + im * c);
  re = bf2f(k[base]);
  im = bf2f(k[base + 1]);
  k[base] = f2bf(re * c - im * s);
  k[base + 1] = f2bf(re * s + im * c);
}

// ---------------- Flash attention (bf16 MFMA, online softmax) ----------------
// grid (64 q-tiles, 16 heads), 256 threads; wave w owns 16 Q rows.
// V is consumed from a GLOBAL V^T [1024][4096] so no LDS transpose is needed.
__global__ __launch_bounds__(256) void attn_kernel(const u16* __restrict__ Q, const u16* __restrict__ Km,
                                                   const u16* __restrict__ VtG, u16* __restrict__ Om) {
  __shared__ uint4 Ks[512];      // K tile 64x64, fragment-contiguous
  __shared__ uint4 Vs[512];      // V^T tile: frag id = db*128 + c*64 + kq*16 + row
  __shared__ uint4 Ps[4][128];   // per-wave P tile 16x64 in A-frag layout (swizzled)
  const int t = threadIdx.x;
  const int w = t >> 6, l = t & 63;
  const int quad = l >> 4, lc = l & 15;
  const int hd = blockIdx.y;
  const int qbase = blockIdx.x * 64;

  bf16x8 aq[2];
  {
    const u16* qp = Q + (size_t)(qbase + w * 16 + lc) * DIMM + hd * HD + quad * 8;
    aq[0] = *(const bf16x8*)qp;
    aq[1] = *(const bf16x8*)(qp + 32);
  }
  const f32x4 zero = {0.0f, 0.0f, 0.0f, 0.0f};
  f32x4 Oa[4];
#pragma unroll
  for (int d = 0; d < 4; d++) Oa[d] = zero;
  float m_r[4], l_r[4];
#pragma unroll
  for (int r = 0; r < 4; r++) { m_r[r] = -1e30f; l_r[r] = 0.0f; }

  // staging address decomposition (both K and Vt tiles, 2 uint4 per thread each)
  const int id0 = t, id1 = t + 256;
  const int b0 = id0 >> 7, c0 = (id0 >> 6) & 1, kq0 = (id0 >> 4) & 3, row0 = id0 & 15;
  const int b1 = id1 >> 7, c1 = (id1 >> 6) & 1, kq1 = (id1 >> 4) & 3, row1 = id1 & 15;
  const u16* Kp0 = Km + (size_t)(b0 * 16 + row0) * DIMM + hd * HD + c0 * 32 + kq0 * 8;
  const u16* Kp1 = Km + (size_t)(b1 * 16 + row1) * DIMM + hd * HD + c1 * 32 + kq1 * 8;
  const u16* Vp0 = VtG + (size_t)(hd * HD + b0 * 16 + row0) * S_LEN + c0 * 32 + kq0 * 8;
  const u16* Vp1 = VtG + (size_t)(hd * HD + b1 * 16 + row1) * S_LEN + c1 * 32 + kq1 * 8;

  const int psw_w = quad << 3;                 // write-side swizzle (bits 3..4 of addr16)
  const int psw_r = ((l >> 2) & 3) << 3;       // read-side swizzle

  for (int kt = 0; kt < S_LEN; kt += 64) {
    gl_lds16(Kp0 + (size_t)kt * DIMM, &Ks[id0]);
    gl_lds16(Kp1 + (size_t)kt * DIMM, &Ks[id1]);
    gl_lds16(Vp0 + kt, &Vs[id0]);
    gl_lds16(Vp1 + kt, &Vs[id1]);
    __syncthreads();

    // S = Q K^T / 8
    f32x4 Sf[4];
#pragma unroll
    for (int s = 0; s < 4; s++) {
      f32x4 z = zero;
      bf16x8 bk0 = *(const bf16x8*)&Ks[s * 128 + l];
      bf16x8 bk1 = *(const bf16x8*)&Ks[s * 128 + 64 + l];
      z = __builtin_amdgcn_mfma_f32_16x16x32_bf16(aq[0], bk0, z, 0, 0, 0);
      z = __builtin_amdgcn_mfma_f32_16x16x32_bf16(aq[1], bk1, z, 0, 0, 0);
      Sf[s] = z * 0.125f;
    }

    // online softmax (row stats over 16-lane groups sharing quad)
    float mn[4], alpha[4], rs[4];
#pragma unroll
    for (int r = 0; r < 4; r++) {
      float mx = fmaxf(fmaxf(Sf[0][r], Sf[1][r]), fmaxf(Sf[2][r], Sf[3][r]));
#pragma unroll
      for (int off = 1; off < 16; off <<= 1) mx = fmaxf(mx, __shfl_xor(mx, off));
      mn[r] = fmaxf(m_r[r], mx);
      alpha[r] = __expf(m_r[r] - mn[r]);
      m_r[r] = mn[r];
      rs[r] = 0.0f;
    }
#pragma unroll
    for (int s = 0; s < 4; s++)
#pragma unroll
      for (int r = 0; r < 4; r++) {
        float p = __expf(Sf[s][r] - mn[r]);
        Sf[s][r] = p;
        rs[r] += p;
      }
#pragma unroll
    for (int r = 0; r < 4; r++) {
#pragma unroll
      for (int off = 1; off < 16; off <<= 1) rs[r] += __shfl_xor(rs[r], off);
      l_r[r] = l_r[r] * alpha[r] + rs[r];
    }
#pragma unroll
    for (int d = 0; d < 4; d++)
#pragma unroll
      for (int r = 0; r < 4; r++) Oa[d][r] *= alpha[r];

    // write P (C-layout) into per-wave LDS in A-frag layout, XOR-swizzled
    {
      u16* pw = (u16*)Ps[w];
#pragma unroll
      for (int s = 0; s < 4; s++) {
        int c = s >> 1;
        int kq = ((s & 1) << 1) + (lc >> 3);
        int jj = lc & 7;
#pragma unroll
        for (int r = 0; r < 4; r++) {
          int m = quad * 4 + r;
          int a16 = (c * 512 + kq * 128 + m * 8 + jj) ^ psw_w;
          pw[a16] = f2bf(Sf[s][r]);
        }
      }
    }
    // PV (per-wave DS in-order: P writes complete before these reads)
    {
      const u16* pw = (const u16*)Ps[w];
#pragma unroll
      for (int c = 0; c < 2; c++) {
        int base = (c * 512 + (l >> 4) * 128 + (l & 15) * 8) ^ psw_r;
        bf16x8 ap = *(const bf16x8*)(pw + base);
#pragma unroll
        for (int d = 0; d < 4; d++) {
          bf16x8 bv = *(const bf16x8*)&Vs[d * 128 + c * 64 + l];
          Oa[d] = __builtin_amdgcn_mfma_f32_16x16x32_bf16(ap, bv, Oa[d], 0, 0, 0);
        }
      }
    }
    __syncthreads();
  }

  // normalize + store
#pragma unroll
  for (int r = 0; r < 4; r++) {
    float inv = 1.0f / l_r[r];
    int row = qbase + w * 16 + quad * 4 + r;
#pragma unroll
    for (int d = 0; d < 4; d++) {
      Om[(size_t)row * DIMM + hd * HD + d * 16 + lc] = f2bf(Oa[d][r] * inv);
    }
  }
}

// ---------------- silu(u) * g elementwise (bf16, in-place into u) ----------------
__global__ __launch_bounds__(256) void silu_mul_kernel(u16* __restrict__ u, const u16* __restrict__ g) {
  int i = (blockIdx.x * 256 + threadIdx.x) * 8;
  u16x8 uv = *(const u16x8*)(u + i);
  u16x8 gv = *(const u16x8*)(g + i);
  u16x8 r;
#pragma unroll
  for (int j = 0; j < 8; j++) {
    float a = bf2f(uv[j]);
    float b = bf2f(gv[j]);
    float sv = a / (1.0f + __expf(-a));
    r[j] = f2bf(sv * b);
  }
  *(u16x8*)(u + i) = r;
}

extern "C" void kernel_launch(void* const* d_in, const int* in_sizes, int n_in,
                              void* d_out, int out_size, void* d_ws, size_t ws_size,
                              hipStream_t stream) {
  const float* x      = (const float*)d_in[0];
  const float* wq     = (const float*)d_in[1];
  const float* wk     = (const float*)d_in[2];
  const float* wv     = (const float*)d_in[3];
  const float* wo     = (const float*)d_in[4];
  const float* w1     = (const float*)d_in[5];
  const float* w2     = (const float*)d_in[6];
  const float* w3     = (const float*)d_in[7];
  const float* g_attn = (const float*)d_in[8];
  const float* g_ffn  = (const float*)d_in[9];
  float* out = (float*)d_out;
  char* ws = (char*)d_ws;
  const size_t MB = 1ull << 20;

  u16* wqb  = (u16*)(ws + 0 * MB);
  u16* wkb  = (u16*)(ws + 2 * MB);
  u16* wvb  = (u16*)(ws + 4 * MB);
  u16* wob  = (u16*)(ws + 6 * MB);
  u16* w1b  = (u16*)(ws + 8 * MB);
  u16* w3b  = (u16*)(ws + 16 * MB);
  u16* w2b  = (u16*)(ws + 24 * MB);
  u16* xnb  = (u16*)(ws + 32 * MB);  // xn, later hn
  u16* qb   = (u16*)(ws + 40 * MB);
  u16* kb   = (u16*)(ws + 48 * MB);
  u16* vtb  = (u16*)(ws + 56 * MB);  // V^T [1024][4096]
  u16* attb = (u16*)(ws + 64 * MB);
  u16* ub   = (u16*)(ws + 40 * MB);  // reuses q/k/vt/att region after o-proj
  u16* gb   = (u16*)(ws + 72 * MB);
  float* cosT = (float*)(ws + 104 * MB);
  float* sinT = (float*)(ws + 104 * MB + 512 * 1024);

  // weights -> bf16
  cvt_bf16_kernel<<<512, 256, 0, stream>>>(wq, wqb);
  cvt_bf16_kernel<<<512, 256, 0, stream>>>(wk, wkb);
  cvt_bf16_kernel<<<512, 256, 0, stream>>>(wv, wvb);
  cvt_bf16_kernel<<<512, 256, 0, stream>>>(wo, wob);
  cvt_bf16_kernel<<<2048, 256, 0, stream>>>(w1, w1b);
  cvt_bf16_kernel<<<2048, 256, 0, stream>>>(w3, w3b);
  cvt_bf16_kernel<<<2048, 256, 0, stream>>>(w2, w2b);
  rope_tables_kernel<<<512, 256, 0, stream>>>(cosT, sinT);

  rmsnorm_kernel<<<4096, 256, 0, stream>>>(x, g_attn, xnb);

  dim3 g1(8, 32);   // N=1024 tiles x M=4096 tiles
  gemm_kernel<0><<<g1, 256, 0, stream>>>(xnb, wqb, qb, nullptr, DIMM, DIMM);
  gemm_kernel<0><<<g1, 256, 0, stream>>>(xnb, wkb, kb, nullptr, DIMM, DIMM);
  // V^T = wv @ xn^T : C[1024][4096]
  gemm_kernel<0><<<dim3(32, 8), 256, 0, stream>>>(wvb, xnb, vtb, nullptr, S_LEN, DIMM);

  rope_apply_kernel<<<8192, 256, 0, stream>>>(qb, kb, cosT, sinT);

  attn_kernel<<<dim3(64, 16), 256, 0, stream>>>(qb, kb, vtb, attb);

  // h = x + attn @ wo^T  (h lives in d_out)
  gemm_kernel<1><<<g1, 256, 0, stream>>>(attb, wob, out, x, DIMM, DIMM);

  rmsnorm_kernel<<<4096, 256, 0, stream>>>(out, g_ffn, xnb);

  dim3 g2(32, 32);  // N=4096 tiles x M=4096 tiles
  gemm_kernel<0><<<g2, 256, 0, stream>>>(xnb, w1b, ub, nullptr, HID, DIMM);
  gemm_kernel<0><<<g2, 256, 0, stream>>>(xnb, w3b, gb, nullptr, HID, DIMM);

  silu_mul_kernel<<<8192, 256, 0, stream>>>(ub, gb);

  // out = h + ff @ w2^T  (in-place residual from d_out)
  gemm_kernel<1><<<g1, 256, 0, stream>>>(ub, w2b, out, out, DIMM, HID);
}

// Round 4
// 725.869 us; speedup vs baseline: 1.2634x; 1.1346x over previous
//
#include <hip/hip_runtime.h>

#define S_LEN 4096
#define DIMM  1024
#define NH    16
#define HD    64
#define HID   4096

typedef unsigned short u16;
typedef __attribute__((ext_vector_type(8))) short bf16x8;
typedef __attribute__((ext_vector_type(4))) short short4b;
typedef __attribute__((ext_vector_type(8))) unsigned short u16x8;
typedef __attribute__((ext_vector_type(4))) float f32x4;

__device__ __forceinline__ u16 f2bf(float f) {
  unsigned u = __float_as_uint(f);
  u += 0x7fffu + ((u >> 16) & 1u);   // round-to-nearest-even
  return (u16)(u >> 16);
}
__device__ __forceinline__ float bf2f(u16 h) {
  return __uint_as_float(((unsigned)h) << 16);
}
// pack two f32 -> (bf16(hi)<<16)|bf16(lo), truncating (1 inst)
__device__ __forceinline__ unsigned pack_bf16(float hi, float lo) {
  return __builtin_amdgcn_perm(__float_as_uint(hi), __float_as_uint(lo), 0x07060302u);
}
// 2^x via v_exp_f32 (avoid glibc __exp2f macro collision)
__device__ __forceinline__ float fexp2(float x) { return __builtin_amdgcn_exp2f(x); }

// async global->LDS, 16B per lane (dest must be wave-uniform base + lane*16)
__device__ __forceinline__ void gl_lds16(const void* g, void* l) {
  __builtin_amdgcn_global_load_lds(
      (const __attribute__((address_space(1))) void*)g,
      (__attribute__((address_space(3))) void*)l, 16, 0, 0);
}

__device__ __forceinline__ f32x4 mfma16(short4b a, short4b b, f32x4 c) {
#if __has_builtin(__builtin_amdgcn_mfma_f32_16x16x16bf16_1k)
  return __builtin_amdgcn_mfma_f32_16x16x16bf16_1k(a, b, c, 0, 0, 0);
#else
  asm("v_mfma_f32_16x16x16_bf16 %0, %1, %2, %0" : "+v"(c) : "v"(a), "v"(b));
  return c;
#endif
}

// ---------------- fp32 -> bf16 convert (8 elems/thread) ----------------
__global__ __launch_bounds__(256) void cvt_bf16_kernel(const float* __restrict__ in, u16* __restrict__ out) {
  int i = (blockIdx.x * 256 + threadIdx.x) * 8;
  float4 a = *(const float4*)(in + i);
  float4 b = *(const float4*)(in + i + 4);
  u16x8 r;
  r[0] = f2bf(a.x); r[1] = f2bf(a.y); r[2] = f2bf(a.z); r[3] = f2bf(a.w);
  r[4] = f2bf(b.x); r[5] = f2bf(b.y); r[6] = f2bf(b.z); r[7] = f2bf(b.w);
  *(u16x8*)(out + i) = r;
}

// ---------------- RMSNorm: fp32 in -> bf16 out ----------------
__global__ __launch_bounds__(256) void rmsnorm_kernel(const float* __restrict__ x, const float* __restrict__ g,
                                                      u16* __restrict__ out) {
  int row = blockIdx.x;
  int t = threadIdx.x;
  const float4 v = *(const float4*)(x + (size_t)row * DIMM + t * 4);
  float ss = v.x * v.x + v.y * v.y + v.z * v.z + v.w * v.w;
#pragma unroll
  for (int off = 32; off > 0; off >>= 1) ss += __shfl_down(ss, off);
  __shared__ float red[4];
  if ((t & 63) == 0) red[t >> 6] = ss;
  __syncthreads();
  float tot = red[0] + red[1] + red[2] + red[3];
  float sc = rsqrtf(tot * (1.0f / DIMM) + 1e-6f);
  const float4 gv = *(const float4*)(g + t * 4);
  ushort4 o;
  o.x = f2bf(v.x * sc * gv.x);
  o.y = f2bf(v.y * sc * gv.y);
  o.z = f2bf(v.z * sc * gv.z);
  o.w = f2bf(v.w * sc * gv.w);
  *(ushort4*)(out + (size_t)row * DIMM + t * 4) = o;
}

// ---------------- bf16 MFMA GEMM: C[M,N] = A[M,K] * B[N,K]^T ----------------
// 128x128 tile, BK=32, 4 waves 2x2, fragment-contiguous LDS, global_load_lds staging.
// OUTMODE 0: store bf16. OUTMODE 1: store fp32 = res + acc. OUTMODE 2: bf16 V-swizzle store.
template <int OUTMODE>
__global__ __launch_bounds__(256) void gemm_kernel(const u16* __restrict__ A, const u16* __restrict__ B,
                                                   void* Cout, const float* res, int N, int K) {
  __shared__ uint4 As[512];
  __shared__ uint4 Bs[512];
  const int t = threadIdx.x;
  const int w = t >> 6, l = t & 63;
  const int bm = blockIdx.y, bn = blockIdx.x;
  const int quad = l >> 4, lc = l & 15;

  f32x4 acc[4][4];
  const f32x4 zero = {0.0f, 0.0f, 0.0f, 0.0f};
#pragma unroll
  for (int mi = 0; mi < 4; mi++)
#pragma unroll
    for (int ni = 0; ni < 4; ni++) acc[mi][ni] = zero;

  const int id0 = t, id1 = t + 256;
  const int band0 = id0 >> 6, kq0 = (id0 >> 4) & 3, row0 = id0 & 15;
  const int band1 = id1 >> 6, kq1 = (id1 >> 4) & 3, row1 = id1 & 15;
  const u16* Ap0 = A + (size_t)(bm * 128 + band0 * 16 + row0) * K + kq0 * 8;
  const u16* Ap1 = A + (size_t)(bm * 128 + band1 * 16 + row1) * K + kq1 * 8;
  const u16* Bp0 = B + (size_t)(bn * 128 + band0 * 16 + row0) * K + kq0 * 8;
  const u16* Bp1 = B + (size_t)(bn * 128 + band1 * 16 + row1) * K + kq1 * 8;
  const int abase = (w >> 1) * 256 + l;
  const int bbase = (w & 1) * 256 + l;

  for (int k0 = 0; k0 < K; k0 += 32) {
    gl_lds16(Ap0 + k0, &As[id0]);
    gl_lds16(Ap1 + k0, &As[id1]);
    gl_lds16(Bp0 + k0, &Bs[id0]);
    gl_lds16(Bp1 + k0, &Bs[id1]);
    __syncthreads();
    bf16x8 af[4], bfr[4];
#pragma unroll
    for (int mi = 0; mi < 4; mi++) af[mi] = *(const bf16x8*)&As[abase + mi * 64];
#pragma unroll
    for (int ni = 0; ni < 4; ni++) bfr[ni] = *(const bf16x8*)&Bs[bbase + ni * 64];
#pragma unroll
    for (int mi = 0; mi < 4; mi++)
#pragma unroll
      for (int ni = 0; ni < 4; ni++)
        acc[mi][ni] = __builtin_amdgcn_mfma_f32_16x16x32_bf16(af[mi], bfr[ni], acc[mi][ni], 0, 0, 0);
    __syncthreads();
  }

  const int rbase = bm * 128 + (w >> 1) * 64 + quad * 4;
  const int cbase = bn * 128 + (w & 1) * 64 + lc;
#pragma unroll
  for (int mi = 0; mi < 4; mi++) {
#pragma unroll
    for (int r = 0; r < 4; r++) {
      int row = rbase + mi * 16 + r;
#pragma unroll
      for (int ni = 0; ni < 4; ni++) {
        int col = cbase + ni * 16;
        if constexpr (OUTMODE == 0) {
          ((u16*)Cout)[(size_t)row * N + col] = f2bf(acc[mi][ni][r]);
        } else if constexpr (OUTMODE == 1) {
          size_t idx = (size_t)row * N + col;
          ((float*)Cout)[idx] = res[idx] + acc[mi][ni][r];
        } else {
          // V-swizzle: row = value-dim d_g, col = key. Layout matches attn Vs LDS image.
          int h = row >> 6, din = row & 63;
          int kb = col >> 6, k63 = col & 63;
          int off = ((h << 6) + kb) * 4096 + (((din >> 4) << 1) + (k63 >> 5)) * 512 +
                    ((((k63 >> 2) & 3) << 4) + (din & 15)) * 8 + ((k63 >> 4) & 1) * 4 + (k63 & 3);
          ((u16*)Cout)[off] = f2bf(acc[mi][ni][r]);
        }
      }
    }
  }
}

// ---------------- RoPE tables (fp64 for phase accuracy) ----------------
__global__ __launch_bounds__(256) void rope_tables_kernel(float* __restrict__ cosT, float* __restrict__ sinT) {
  int idx = blockIdx.x * 256 + threadIdx.x;  // 4096*32
  int pos = idx >> 5, i = idx & 31;
  double inv = pow(10000.0, -(double)(2 * i) / 64.0);
  double a = (double)pos * inv;
  cosT[idx] = (float)cos(a);
  sinT[idx] = (float)sin(a);
}

// qk buffer: [4096 rows][2048 cols]: cols 0..1023 = Q, 1024..2047 = K
__global__ __launch_bounds__(256) void rope_apply_kernel(u16* __restrict__ qk,
                                                         const float* __restrict__ cosT,
                                                         const float* __restrict__ sinT) {
  int idx = blockIdx.x * 256 + threadIdx.x;  // 4096*16*32
  int pos = idx >> 9, h = (idx >> 5) & 15, i = idx & 31;
  float c = cosT[(pos << 5) + i], s = sinT[(pos << 5) + i];
  size_t base = (size_t)pos * 2048 + h * HD + 2 * i;
  float re = bf2f(qk[base]), im = bf2f(qk[base + 1]);
  qk[base] = f2bf(re * c - im * s);
  qk[base + 1] = f2bf(re * s + im * c);
  re = bf2f(qk[base + 1024]);
  im = bf2f(qk[base + 1025]);
  qk[base + 1024] = f2bf(re * c - im * s);
  qk[base + 1025] = f2bf(re * s + im * c);
}

// ---------------- Flash attention, transposed orientation ----------------
// S^T = K*Q^T per 64-key tile; exp'd S^T C-frags feed 16x16x16 PV directly (no LDS roundtrip).
// Block: 4 waves x 32 queries = 128 q rows, one head. Grid (32, 16).
__global__ __launch_bounds__(256) void attn_kernel(const u16* __restrict__ Qm, const u16* __restrict__ Km,
                                                   const u16* __restrict__ Vsw, u16* __restrict__ Om) {
  __shared__ char smem[18432];
  uint4* Ks = (uint4*)smem;             // 8KB: K tile [64 keys][64 d], A32-frag contiguous
  uint4* Vs = (uint4*)(smem + 8192);    // 8KB: V^T tile, A16-frag-pair contiguous
  const int t = threadIdx.x;
  const int w = t >> 6, l = t & 63;
  const int quad = l >> 4, lc = l & 15;
  const int hd = blockIdx.y;
  const int qrow = blockIdx.x * 128 + w * 32;

  // Q B-frags (loop-invariant, registers)
  bf16x8 qf_[2][2];
#pragma unroll
  for (int qf = 0; qf < 2; qf++)
#pragma unroll
    for (int ch = 0; ch < 2; ch++)
      qf_[qf][ch] = *(const bf16x8*)(Qm + (size_t)(qrow + qf * 16 + lc) * 2048 + hd * HD + ch * 32 + quad * 8);

  const f32x4 zero = {0.0f, 0.0f, 0.0f, 0.0f};
  f32x4 Oa[4][2];
#pragma unroll
  for (int df = 0; df < 4; df++)
#pragma unroll
    for (int qf = 0; qf < 2; qf++) Oa[df][qf] = zero;
  float mt[2] = {-1e30f, -1e30f}, ls[2] = {0.0f, 0.0f};

  // K staging addresses (stride 2048; id = s*128 + c*64 + kq*16 + row)
  const int s0 = t >> 7, c0 = (t >> 6) & 1, kq0 = (t >> 4) & 3, row0 = t & 15;
  const int id1 = t + 256;
  const int s1 = id1 >> 7, c1 = (id1 >> 6) & 1, kq1 = (id1 >> 4) & 3, row1 = id1 & 15;
  const u16* Kp0 = Km + (size_t)(s0 * 16 + row0) * 2048 + hd * HD + c0 * 32 + kq0 * 8;
  const u16* Kp1 = Km + (size_t)(s1 * 16 + row1) * 2048 + hd * HD + c1 * 32 + kq1 * 8;
  const u16* Vp = Vsw + (size_t)(hd * HD) * 4096 + t * 8;
  const float csc = 0.125f * 1.44269504088896f;  // 1/sqrt(64) * log2(e)

  for (int kt = 0; kt < S_LEN; kt += 64) {
    gl_lds16(Kp0 + (size_t)kt * 2048, &Ks[t]);
    gl_lds16(Kp1 + (size_t)kt * 2048, &Ks[t + 256]);
    const u16* vp = Vp + (size_t)(kt >> 6) * 4096;
    gl_lds16(vp, &Vs[t]);
    gl_lds16(vp + 2048, &Vs[t + 256]);
    __syncthreads();

    // S^T = K Q^T, scaled into exp2-space
    f32x4 Sf[4][2];
#pragma unroll
    for (int kf = 0; kf < 4; kf++) {
      bf16x8 ka = *(const bf16x8*)&Ks[kf * 128 + l];
      bf16x8 kb2 = *(const bf16x8*)&Ks[kf * 128 + 64 + l];
#pragma unroll
      for (int qf = 0; qf < 2; qf++) {
        f32x4 z = __builtin_amdgcn_mfma_f32_16x16x32_bf16(ka, qf_[qf][0], zero, 0, 0, 0);
        z = __builtin_amdgcn_mfma_f32_16x16x32_bf16(kb2, qf_[qf][1], z, 0, 0, 0);
        Sf[kf][qf] = z * csc;
      }
    }

    // online softmax per qf (keys live in regs+quads: in-reg reduce + 2 swizzles)
    short4b pk[4][2];
#pragma unroll
    for (int qf = 0; qf < 2; qf++) {
      float tmax = -1e30f;
#pragma unroll
      for (int kf = 0; kf < 4; kf++)
#pragma unroll
        for (int r = 0; r < 4; r++) tmax = fmaxf(tmax, Sf[kf][qf][r]);
      tmax = fmaxf(tmax, __shfl_xor(tmax, 16));
      tmax = fmaxf(tmax, __shfl_xor(tmax, 32));
      float mnew = fmaxf(mt[qf], tmax);
      float alpha = fexp2(mt[qf] - mnew);
      mt[qf] = mnew;
      float psum = 0.0f;
#pragma unroll
      for (int kf = 0; kf < 4; kf++) {
#pragma unroll
        for (int r = 0; r < 4; r++) {
          float p = fexp2(Sf[kf][qf][r] - mnew);
          Sf[kf][qf][r] = p;
          psum += p;
        }
      }
      psum += __shfl_xor(psum, 16);
      psum += __shfl_xor(psum, 32);
      ls[qf] = ls[qf] * alpha + psum;
#pragma unroll
      for (int df = 0; df < 4; df++) Oa[df][qf] *= alpha;
      // pack exp'd S^T frags into PV B-operands (C-layout == B16-layout)
#pragma unroll
      for (int kf = 0; kf < 4; kf++) {
        union { short4b s4; uint2 u2; } cv;
        cv.u2.x = pack_bf16(Sf[kf][qf][1], Sf[kf][qf][0]);
        cv.u2.y = pack_bf16(Sf[kf][qf][3], Sf[kf][qf][2]);
        pk[kf][qf] = cv.s4;
      }
    }

    // O^T += V^T * P^T  (16x16x16 MFMAs)
#pragma unroll
    for (int df = 0; df < 4; df++)
#pragma unroll
      for (int tp = 0; tp < 2; tp++) {
        union { bf16x8 v8; short4b h[2]; } vv;
        vv.v8 = *(const bf16x8*)&Vs[(df * 2 + tp) * 64 + l];
#pragma unroll
        for (int qf = 0; qf < 2; qf++) {
          Oa[df][qf] = mfma16(vv.h[0], pk[2 * tp][qf], Oa[df][qf]);
          Oa[df][qf] = mfma16(vv.h[1], pk[2 * tp + 1][qf], Oa[df][qf]);
        }
      }
    __syncthreads();
  }

  // epilogue: O^T frags -> LDS [128 q][64 d] (stride 72) -> coalesced global
  u16* ep = (u16*)smem;
  float invl[2] = {1.0f / ls[0], 1.0f / ls[1]};
#pragma unroll
  for (int df = 0; df < 4; df++)
#pragma unroll
    for (int qf = 0; qf < 2; qf++) {
      int qb = w * 32 + qf * 16 + lc;
      int d = df * 16 + quad * 4;
      uint2 pv;
      pv.x = pack_bf16(Oa[df][qf][1] * invl[qf], Oa[df][qf][0] * invl[qf]);
      pv.y = pack_bf16(Oa[df][qf][3] * invl[qf], Oa[df][qf][2] * invl[qf]);
      *(uint2*)(ep + qb * 72 + d) = pv;
    }
  __syncthreads();
#pragma unroll
  for (int it = 0; it < 4; it++) {
    int qb = it * 32 + (t >> 3);
    int dp = (t & 7) * 8;
    u16x8 rowv = *(const u16x8*)(ep + qb * 72 + dp);
    *(u16x8*)(Om + (size_t)(blockIdx.x * 128 + qb) * DIMM + hd * HD + dp) = rowv;
  }
}

// ---------------- silu(u) * g elementwise (bf16, in-place into u) ----------------
__global__ __launch_bounds__(256) void silu_mul_kernel(u16* __restrict__ u, const u16* __restrict__ g) {
  int i = (blockIdx.x * 256 + threadIdx.x) * 8;
  u16x8 uv = *(const u16x8*)(u + i);
  u16x8 gv = *(const u16x8*)(g + i);
  u16x8 r;
#pragma unroll
  for (int j = 0; j < 8; j++) {
    float a = bf2f(uv[j]);
    float b = bf2f(gv[j]);
    float sv = a / (1.0f + __expf(-a));
    r[j] = f2bf(sv * b);
  }
  *(u16x8*)(u + i) = r;
}

extern "C" void kernel_launch(void* const* d_in, const int* in_sizes, int n_in,
                              void* d_out, int out_size, void* d_ws, size_t ws_size,
                              hipStream_t stream) {
  const float* x      = (const float*)d_in[0];
  const float* wq     = (const float*)d_in[1];
  const float* wk     = (const float*)d_in[2];
  const float* wv     = (const float*)d_in[3];
  const float* wo     = (const float*)d_in[4];
  const float* w1     = (const float*)d_in[5];
  const float* w2     = (const float*)d_in[6];
  const float* w3     = (const float*)d_in[7];
  const float* g_attn = (const float*)d_in[8];
  const float* g_ffn  = (const float*)d_in[9];
  float* out = (float*)d_out;
  char* ws = (char*)d_ws;
  const size_t MB = 1ull << 20;

  u16* wqkb = (u16*)(ws + 0 * MB);    // [2048][1024]: rows 0-1023 wq, 1024-2047 wk
  u16* wvb  = (u16*)(ws + 4 * MB);
  u16* wob  = (u16*)(ws + 6 * MB);
  u16* w1b  = (u16*)(ws + 8 * MB);
  u16* w3b  = (u16*)(ws + 16 * MB);
  u16* w2b  = (u16*)(ws + 24 * MB);
  u16* xnb  = (u16*)(ws + 32 * MB);   // xn, later hn
  u16* qkb  = (u16*)(ws + 40 * MB);   // [4096][2048]
  u16* vswz = (u16*)(ws + 56 * MB);   // V^T swizzled, 8MB
  u16* attb = (u16*)(ws + 64 * MB);
  u16* ub   = (u16*)(ws + 40 * MB);   // reuses qk/vswz/att region after o-proj
  u16* gb   = (u16*)(ws + 72 * MB);
  float* cosT = (float*)(ws + 104 * MB);
  float* sinT = (float*)(ws + 104 * MB + 512 * 1024);

  // weights -> bf16
  cvt_bf16_kernel<<<512, 256, 0, stream>>>(wq, wqkb);
  cvt_bf16_kernel<<<512, 256, 0, stream>>>(wk, wqkb + 1024 * 1024);
  cvt_bf16_kernel<<<512, 256, 0, stream>>>(wv, wvb);
  cvt_bf16_kernel<<<512, 256, 0, stream>>>(wo, wob);
  cvt_bf16_kernel<<<2048, 256, 0, stream>>>(w1, w1b);
  cvt_bf16_kernel<<<2048, 256, 0, stream>>>(w3, w3b);
  cvt_bf16_kernel<<<2048, 256, 0, stream>>>(w2, w2b);
  rope_tables_kernel<<<512, 256, 0, stream>>>(cosT, sinT);

  rmsnorm_kernel<<<4096, 256, 0, stream>>>(x, g_attn, xnb);

  // QK fused: C[4096][2048]
  gemm_kernel<0><<<dim3(16, 32), 256, 0, stream>>>(xnb, wqkb, qkb, nullptr, 2048, DIMM);
  // V^T = wv @ xn^T, swizzle-stored
  gemm_kernel<2><<<dim3(32, 8), 256, 0, stream>>>(wvb, xnb, vswz, nullptr, S_LEN, DIMM);

  rope_apply_kernel<<<8192, 256, 0, stream>>>(qkb, cosT, sinT);

  attn_kernel<<<dim3(32, 16), 256, 0, stream>>>(qkb, qkb + 1024, vswz, attb);

  // h = x + attn @ wo^T  (h lives in d_out)
  gemm_kernel<1><<<dim3(8, 32), 256, 0, stream>>>(attb, wob, out, x, DIMM, DIMM);

  rmsnorm_kernel<<<4096, 256, 0, stream>>>(out, g_ffn, xnb);

  gemm_kernel<0><<<dim3(32, 32), 256, 0, stream>>>(xnb, w1b, ub, nullptr, HID, DIMM);
  gemm_kernel<0><<<dim3(32, 32), 256, 0, stream>>>(xnb, w3b, gb, nullptr, HID, DIMM);

  silu_mul_kernel<<<8192, 256, 0, stream>>>(ub, gb);

  // out = h + ff @ w2^T  (in-place residual from d_out)
  gemm_kernel<1><<<dim3(8, 32), 256, 0, stream>>>(ub, w2b, out, out, DIMM, HID);
}

// Round 6
// 705.681 us; speedup vs baseline: 1.2996x; 1.0286x over previous
//
#include <hip/hip_runtime.h>

#define S_LEN 4096
#define DIMM  1024
#define NH    16
#define HD    64
#define HID   4096

typedef unsigned short u16;
typedef __attribute__((ext_vector_type(8))) short bf16x8;
typedef __attribute__((ext_vector_type(4))) short short4b;
typedef __attribute__((ext_vector_type(8))) unsigned short u16x8;
typedef __attribute__((ext_vector_type(4))) float f32x4;

__device__ __forceinline__ u16 f2bf(float f) {
  unsigned u = __float_as_uint(f);
  u += 0x7fffu + ((u >> 16) & 1u);   // round-to-nearest-even
  return (u16)(u >> 16);
}
__device__ __forceinline__ float bf2f(u16 h) {
  return __uint_as_float(((unsigned)h) << 16);
}
// pack two f32 -> (bf16(hi)<<16)|bf16(lo), truncating (1 inst)
__device__ __forceinline__ unsigned pack_bf16(float hi, float lo) {
  return __builtin_amdgcn_perm(__float_as_uint(hi), __float_as_uint(lo), 0x07060302u);
}
// 2^x via v_exp_f32 (avoid glibc __exp2f macro collision)
__device__ __forceinline__ float fexp2(float x) { return __builtin_amdgcn_exp2f(x); }

// async global->LDS, 16B per lane (dest must be wave-uniform base + lane*16)
__device__ __forceinline__ void gl_lds16(const void* g, void* l) {
  __builtin_amdgcn_global_load_lds(
      (const __attribute__((address_space(1))) void*)g,
      (__attribute__((address_space(3))) void*)l, 16, 0, 0);
}

__device__ __forceinline__ f32x4 mfma16(short4b a, short4b b, f32x4 c) {
#if __has_builtin(__builtin_amdgcn_mfma_f32_16x16x16bf16_1k)
  return __builtin_amdgcn_mfma_f32_16x16x16bf16_1k(a, b, c, 0, 0, 0);
#else
  asm("v_mfma_f32_16x16x16_bf16 %0, %1, %2, %0" : "+v"(c) : "v"(a), "v"(b));
  return c;
#endif
}

// ---------------- fp32 -> bf16 convert (8 elems/thread) ----------------
__global__ __launch_bounds__(256) void cvt_bf16_kernel(const float* __restrict__ in, u16* __restrict__ out) {
  int i = (blockIdx.x * 256 + threadIdx.x) * 8;
  float4 a = *(const float4*)(in + i);
  float4 b = *(const float4*)(in + i + 4);
  u16x8 r;
  r[0] = f2bf(a.x); r[1] = f2bf(a.y); r[2] = f2bf(a.z); r[3] = f2bf(a.w);
  r[4] = f2bf(b.x); r[5] = f2bf(b.y); r[6] = f2bf(b.z); r[7] = f2bf(b.w);
  *(u16x8*)(out + i) = r;
}

// ---------------- RMSNorm: fp32 in -> bf16 out ----------------
__global__ __launch_bounds__(256) void rmsnorm_kernel(const float* __restrict__ x, const float* __restrict__ g,
                                                      u16* __restrict__ out) {
  int row = blockIdx.x;
  int t = threadIdx.x;
  const float4 v = *(const float4*)(x + (size_t)row * DIMM + t * 4);
  float ss = v.x * v.x + v.y * v.y + v.z * v.z + v.w * v.w;
#pragma unroll
  for (int off = 32; off > 0; off >>= 1) ss += __shfl_down(ss, off);
  __shared__ float red[4];
  if ((t & 63) == 0) red[t >> 6] = ss;
  __syncthreads();
  float tot = red[0] + red[1] + red[2] + red[3];
  float sc = rsqrtf(tot * (1.0f / DIMM) + 1e-6f);
  const float4 gv = *(const float4*)(g + t * 4);
  ushort4 o;
  o.x = f2bf(v.x * sc * gv.x);
  o.y = f2bf(v.y * sc * gv.y);
  o.z = f2bf(v.z * sc * gv.z);
  o.w = f2bf(v.w * sc * gv.w);
  *(ushort4*)(out + (size_t)row * DIMM + t * 4) = o;
}

// ---------------- bf16 MFMA GEMM: C[M,N] = A[M,K] * B[N,K]^T ----------------
// 128x128 tile, BK=32, 4 waves 2x2, fragment-contiguous LDS, global_load_lds staging.
// lda = A row stride. OUTMODE 0: bf16. OUTMODE 1: fp32 = res + acc. OUTMODE 2: bf16 V-swizzle.
template <int OUTMODE>
__global__ __launch_bounds__(256) void gemm_kernel(const u16* __restrict__ A, const u16* __restrict__ B,
                                                   void* Cout, const float* res, int N, int K, int lda) {
  __shared__ uint4 As[512];
  __shared__ uint4 Bs[512];
  const int t = threadIdx.x;
  const int w = t >> 6, l = t & 63;
  const int bm = blockIdx.y, bn = blockIdx.x;
  const int quad = l >> 4, lc = l & 15;

  f32x4 acc[4][4];
  const f32x4 zero = {0.0f, 0.0f, 0.0f, 0.0f};
#pragma unroll
  for (int mi = 0; mi < 4; mi++)
#pragma unroll
    for (int ni = 0; ni < 4; ni++) acc[mi][ni] = zero;

  const int id0 = t, id1 = t + 256;
  const int band0 = id0 >> 6, kq0 = (id0 >> 4) & 3, row0 = id0 & 15;
  const int band1 = id1 >> 6, kq1 = (id1 >> 4) & 3, row1 = id1 & 15;
  const u16* Ap0 = A + (size_t)(bm * 128 + band0 * 16 + row0) * lda + kq0 * 8;
  const u16* Ap1 = A + (size_t)(bm * 128 + band1 * 16 + row1) * lda + kq1 * 8;
  const u16* Bp0 = B + (size_t)(bn * 128 + band0 * 16 + row0) * K + kq0 * 8;
  const u16* Bp1 = B + (size_t)(bn * 128 + band1 * 16 + row1) * K + kq1 * 8;
  const int abase = (w >> 1) * 256 + l;
  const int bbase = (w & 1) * 256 + l;

  for (int k0 = 0; k0 < K; k0 += 32) {
    gl_lds16(Ap0 + k0, &As[id0]);
    gl_lds16(Ap1 + k0, &As[id1]);
    gl_lds16(Bp0 + k0, &Bs[id0]);
    gl_lds16(Bp1 + k0, &Bs[id1]);
    __syncthreads();
    bf16x8 af[4], bfr[4];
#pragma unroll
    for (int mi = 0; mi < 4; mi++) af[mi] = *(const bf16x8*)&As[abase + mi * 64];
#pragma unroll
    for (int ni = 0; ni < 4; ni++) bfr[ni] = *(const bf16x8*)&Bs[bbase + ni * 64];
#pragma unroll
    for (int mi = 0; mi < 4; mi++)
#pragma unroll
      for (int ni = 0; ni < 4; ni++)
        acc[mi][ni] = __builtin_amdgcn_mfma_f32_16x16x32_bf16(af[mi], bfr[ni], acc[mi][ni], 0, 0, 0);
    __syncthreads();
  }

  const int rbase = bm * 128 + (w >> 1) * 64 + quad * 4;
  const int cbase = bn * 128 + (w & 1) * 64 + lc;
#pragma unroll
  for (int mi = 0; mi < 4; mi++) {
#pragma unroll
    for (int r = 0; r < 4; r++) {
      int row = rbase + mi * 16 + r;
#pragma unroll
      for (int ni = 0; ni < 4; ni++) {
        int col = cbase + ni * 16;
        if constexpr (OUTMODE == 0) {
          ((u16*)Cout)[(size_t)row * N + col] = f2bf(acc[mi][ni][r]);
        } else if constexpr (OUTMODE == 1) {
          size_t idx = (size_t)row * N + col;
          ((float*)Cout)[idx] = res[idx] + acc[mi][ni][r];
        } else {
          // V-swizzle: row = value-dim, col = key. Produces the V^T fragment image.
          int h = row >> 6, din = row & 63;
          int kb = col >> 6, k63 = col & 63;
          int off = ((h << 6) + kb) * 4096 + (((din >> 4) << 1) + (k63 >> 5)) * 512 +
                    ((((k63 >> 2) & 3) << 4) + (din & 15)) * 8 + ((k63 >> 4) & 1) * 4 + (k63 & 3);
          ((u16*)Cout)[off] = f2bf(acc[mi][ni][r]);
        }
      }
    }
  }
}

// ---------------- RoPE tables (fp64 for phase accuracy) ----------------
__global__ __launch_bounds__(256) void rope_tables_kernel(float* __restrict__ cosT, float* __restrict__ sinT) {
  int idx = blockIdx.x * 256 + threadIdx.x;  // 4096*32
  int pos = idx >> 5, i = idx & 31;
  double inv = pow(10000.0, -(double)(2 * i) / 64.0);
  double a = (double)pos * inv;
  cosT[idx] = (float)cos(a);
  sinT[idx] = (float)sin(a);
}

// qk buffer: [4096 rows][2048 cols]: cols 0..1023 = Q, 1024..2047 = K (both roped in place)
__global__ __launch_bounds__(256) void rope_apply_kernel(u16* __restrict__ qk,
                                                         const float* __restrict__ cosT,
                                                         const float* __restrict__ sinT) {
  int idx = blockIdx.x * 256 + threadIdx.x;  // 4096*16*32
  int pos = idx >> 9, h = (idx >> 5) & 15, i = idx & 31;
  float c = cosT[(pos << 5) + i], s = sinT[(pos << 5) + i];
  size_t base = (size_t)pos * 2048 + h * HD + 2 * i;
  float re = bf2f(qk[base]), im = bf2f(qk[base + 1]);
  qk[base] = f2bf(re * c - im * s);
  qk[base + 1] = f2bf(re * s + im * c);
  re = bf2f(qk[base + 1024]);
  im = bf2f(qk[base + 1025]);
  qk[base + 1024] = f2bf(re * c - im * s);
  qk[base + 1025] = f2bf(re * s + im * c);
}

// ---------------- Flash attention, transposed orientation (round-4 proven) ----------------
// S^T = K*Q^T per 64-key tile; exp'd S^T C-frags feed 16x16x16 PV directly (no LDS roundtrip).
// Block: 4 waves x 32 queries = 128 q rows, one head. Grid (32, 16).
__global__ __launch_bounds__(256) void attn_kernel(const u16* __restrict__ Qm, const u16* __restrict__ Km,
                                                   const u16* __restrict__ Vsw, u16* __restrict__ Om) {
  __shared__ char smem[18432];
  uint4* Ks = (uint4*)smem;             // 8KB: K tile [64 keys][64 d], A32-frag contiguous
  uint4* Vs = (uint4*)(smem + 8192);    // 8KB: V^T tile, A16-frag-pair contiguous
  const int t = threadIdx.x;
  const int w = t >> 6, l = t & 63;
  const int quad = l >> 4, lc = l & 15;
  const int hd = blockIdx.y;
  const int qrow = blockIdx.x * 128 + w * 32;

  // Q B-frags (loop-invariant, registers)
  bf16x8 qf_[2][2];
#pragma unroll
  for (int qf = 0; qf < 2; qf++)
#pragma unroll
    for (int ch = 0; ch < 2; ch++)
      qf_[qf][ch] = *(const bf16x8*)(Qm + (size_t)(qrow + qf * 16 + lc) * 2048 + hd * HD + ch * 32 + quad * 8);

  const f32x4 zero = {0.0f, 0.0f, 0.0f, 0.0f};
  f32x4 Oa[4][2];
#pragma unroll
  for (int df = 0; df < 4; df++)
#pragma unroll
    for (int qf = 0; qf < 2; qf++) Oa[df][qf] = zero;
  float mt[2] = {-1e30f, -1e30f}, ls[2] = {0.0f, 0.0f};

  // K staging addresses (stride 2048; id = s*128 + c*64 + kq*16 + row)
  const int s0 = t >> 7, c0 = (t >> 6) & 1, kq0 = (t >> 4) & 3, row0 = t & 15;
  const int id1 = t + 256;
  const int s1 = id1 >> 7, c1 = (id1 >> 6) & 1, kq1 = (id1 >> 4) & 3, row1 = id1 & 15;
  const u16* Kp0 = Km + (size_t)(s0 * 16 + row0) * 2048 + hd * HD + c0 * 32 + kq0 * 8;
  const u16* Kp1 = Km + (size_t)(s1 * 16 + row1) * 2048 + hd * HD + c1 * 32 + kq1 * 8;
  const u16* Vp = Vsw + (size_t)(hd * HD) * 4096 + t * 8;
  const float csc = 0.125f * 1.44269504088896f;  // 1/sqrt(64) * log2(e)

  for (int kt = 0; kt < S_LEN; kt += 64) {
    gl_lds16(Kp0 + (size_t)kt * 2048, &Ks[t]);
    gl_lds16(Kp1 + (size_t)kt * 2048, &Ks[t + 256]);
    const u16* vp = Vp + (size_t)(kt >> 6) * 4096;
    gl_lds16(vp, &Vs[t]);
    gl_lds16(vp + 2048, &Vs[t + 256]);
    __syncthreads();

    // S^T = K Q^T, scaled into exp2-space
    f32x4 Sf[4][2];
#pragma unroll
    for (int kf = 0; kf < 4; kf++) {
      bf16x8 ka = *(const bf16x8*)&Ks[kf * 128 + l];
      bf16x8 kb2 = *(const bf16x8*)&Ks[kf * 128 + 64 + l];
#pragma unroll
      for (int qf = 0; qf < 2; qf++) {
        f32x4 z = __builtin_amdgcn_mfma_f32_16x16x32_bf16(ka, qf_[qf][0], zero, 0, 0, 0);
        z = __builtin_amdgcn_mfma_f32_16x16x32_bf16(kb2, qf_[qf][1], z, 0, 0, 0);
        Sf[kf][qf] = z * csc;
      }
    }

    // online softmax per qf (keys live in regs+quads: in-reg reduce + 2 swizzles)
    short4b pk[4][2];
#pragma unroll
    for (int qf = 0; qf < 2; qf++) {
      float tmax = -1e30f;
#pragma unroll
      for (int kf = 0; kf < 4; kf++)
#pragma unroll
        for (int r = 0; r < 4; r++) tmax = fmaxf(tmax, Sf[kf][qf][r]);
      tmax = fmaxf(tmax, __shfl_xor(tmax, 16));
      tmax = fmaxf(tmax, __shfl_xor(tmax, 32));
      float mnew = fmaxf(mt[qf], tmax);
      float alpha = fexp2(mt[qf] - mnew);
      mt[qf] = mnew;
      float psum = 0.0f;
#pragma unroll
      for (int kf = 0; kf < 4; kf++) {
#pragma unroll
        for (int r = 0; r < 4; r++) {
          float p = fexp2(Sf[kf][qf][r] - mnew);
          Sf[kf][qf][r] = p;
          psum += p;
        }
      }
      psum += __shfl_xor(psum, 16);
      psum += __shfl_xor(psum, 32);
      ls[qf] = ls[qf] * alpha + psum;
#pragma unroll
      for (int df = 0; df < 4; df++) Oa[df][qf] *= alpha;
      // pack exp'd S^T frags into PV B-operands (C-layout == B16-layout)
#pragma unroll
      for (int kf = 0; kf < 4; kf++) {
        union { short4b s4; uint2 u2; } cv;
        cv.u2.x = pack_bf16(Sf[kf][qf][1], Sf[kf][qf][0]);
        cv.u2.y = pack_bf16(Sf[kf][qf][3], Sf[kf][qf][2]);
        pk[kf][qf] = cv.s4;
      }
    }

    // O^T += V^T * P^T  (16x16x16 MFMAs)
#pragma unroll
    for (int df = 0; df < 4; df++)
#pragma unroll
      for (int tp = 0; tp < 2; tp++) {
        union { bf16x8 v8; short4b h[2]; } vv;
        vv.v8 = *(const bf16x8*)&Vs[(df * 2 + tp) * 64 + l];
#pragma unroll
        for (int qf = 0; qf < 2; qf++) {
          Oa[df][qf] = mfma16(vv.h[0], pk[2 * tp][qf], Oa[df][qf]);
          Oa[df][qf] = mfma16(vv.h[1], pk[2 * tp + 1][qf], Oa[df][qf]);
        }
      }
    __syncthreads();
  }

  // epilogue: O^T frags -> LDS [128 q][64 d] (stride 72) -> coalesced global
  u16* ep = (u16*)smem;
  float invl[2] = {1.0f / ls[0], 1.0f / ls[1]};
#pragma unroll
  for (int df = 0; df < 4; df++)
#pragma unroll
    for (int qf = 0; qf < 2; qf++) {
      int qb = w * 32 + qf * 16 + lc;
      int d = df * 16 + quad * 4;
      uint2 pv;
      pv.x = pack_bf16(Oa[df][qf][1] * invl[qf], Oa[df][qf][0] * invl[qf]);
      pv.y = pack_bf16(Oa[df][qf][3] * invl[qf], Oa[df][qf][2] * invl[qf]);
      *(uint2*)(ep + qb * 72 + d) = pv;
    }
  __syncthreads();
#pragma unroll
  for (int it = 0; it < 4; it++) {
    int qb = it * 32 + (t >> 3);
    int dp = (t & 7) * 8;
    u16x8 rowv = *(const u16x8*)(ep + qb * 72 + dp);
    *(u16x8*)(Om + (size_t)(blockIdx.x * 128 + qb) * DIMM + hd * HD + dp) = rowv;
  }
}

// ---------------- silu(u) * g on fused [4096][8192] buffer (u cols 0..4095, g cols 4096..8191) ----
__global__ __launch_bounds__(256) void silu_mul_kernel(u16* __restrict__ u13) {
  int i = (blockIdx.x * 256 + threadIdx.x) * 8;
  int r = i >> 12, c = i & 4095;
  u16* up = u13 + (size_t)r * 8192 + c;
  u16x8 uv = *(const u16x8*)up;
  u16x8 gv = *(const u16x8*)(up + 4096);
  u16x8 o;
#pragma unroll
  for (int j = 0; j < 8; j++) {
    float a = bf2f(uv[j]);
    float b = bf2f(gv[j]);
    float sv = a / (1.0f + __expf(-a));
    o[j] = f2bf(sv * b);
  }
  *(u16x8*)up = o;
}

extern "C" void kernel_launch(void* const* d_in, const int* in_sizes, int n_in,
                              void* d_out, int out_size, void* d_ws, size_t ws_size,
                              hipStream_t stream) {
  const float* x      = (const float*)d_in[0];
  const float* wq     = (const float*)d_in[1];
  const float* wk     = (const float*)d_in[2];
  const float* wv     = (const float*)d_in[3];
  const float* wo     = (const float*)d_in[4];
  const float* w1     = (const float*)d_in[5];
  const float* w2     = (const float*)d_in[6];
  const float* w3     = (const float*)d_in[7];
  const float* g_attn = (const float*)d_in[8];
  const float* g_ffn  = (const float*)d_in[9];
  float* out = (float*)d_out;
  char* ws = (char*)d_ws;
  const size_t MB = 1ull << 20;

  u16* wqkb = (u16*)(ws + 0 * MB);    // [2048][1024]: rows 0-1023 wq, 1024-2047 wk
  u16* wvb  = (u16*)(ws + 4 * MB);
  u16* wob  = (u16*)(ws + 6 * MB);
  u16* w13b = (u16*)(ws + 8 * MB);    // [8192][1024]: rows 0-4095 w1, 4096-8191 w3
  u16* w2b  = (u16*)(ws + 24 * MB);
  u16* xnb  = (u16*)(ws + 32 * MB);   // xn, later hn
  u16* qkb  = (u16*)(ws + 40 * MB);   // [4096][2048]
  u16* vswz = (u16*)(ws + 56 * MB);   // V^T fragment image, 8MB
  u16* attb = (u16*)(ws + 64 * MB);
  u16* u13  = (u16*)(ws + 40 * MB);   // [4096][8192], reuses qk/vswz/att region after o-proj
  float* cosT = (float*)(ws + 104 * MB);
  float* sinT = (float*)(ws + 104 * MB + 512 * 1024);

  // weights -> bf16
  cvt_bf16_kernel<<<512, 256, 0, stream>>>(wq, wqkb);
  cvt_bf16_kernel<<<512, 256, 0, stream>>>(wk, wqkb + 1024 * 1024);
  cvt_bf16_kernel<<<512, 256, 0, stream>>>(wv, wvb);
  cvt_bf16_kernel<<<512, 256, 0, stream>>>(wo, wob);
  cvt_bf16_kernel<<<2048, 256, 0, stream>>>(w1, w13b);
  cvt_bf16_kernel<<<2048, 256, 0, stream>>>(w3, w13b + 4096 * 1024);
  cvt_bf16_kernel<<<2048, 256, 0, stream>>>(w2, w2b);
  rope_tables_kernel<<<512, 256, 0, stream>>>(cosT, sinT);

  rmsnorm_kernel<<<4096, 256, 0, stream>>>(x, g_attn, xnb);

  // QK fused: C[4096][2048]
  gemm_kernel<0><<<dim3(16, 32), 256, 0, stream>>>(xnb, wqkb, qkb, nullptr, 2048, DIMM, DIMM);
  // V^T = wv @ xn^T, stored as fragment image
  gemm_kernel<2><<<dim3(32, 8), 256, 0, stream>>>(wvb, xnb, vswz, nullptr, S_LEN, DIMM, DIMM);

  rope_apply_kernel<<<8192, 256, 0, stream>>>(qkb, cosT, sinT);

  attn_kernel<<<dim3(32, 16), 256, 0, stream>>>(qkb, qkb + 1024, vswz, attb);

  // h = x + attn @ wo^T  (h lives in d_out)
  gemm_kernel<1><<<dim3(8, 32), 256, 0, stream>>>(attb, wob, out, x, DIMM, DIMM, DIMM);

  rmsnorm_kernel<<<4096, 256, 0, stream>>>(out, g_ffn, xnb);

  // fused W1|W3: [4096][8192]
  gemm_kernel<0><<<dim3(64, 32), 256, 0, stream>>>(xnb, w13b, u13, nullptr, 8192, DIMM, DIMM);

  silu_mul_kernel<<<8192, 256, 0, stream>>>(u13);

  // out = h + ff @ w2^T  (A = u half of u13, lda = 8192; in-place residual from d_out)
  gemm_kernel<1><<<dim3(8, 32), 256, 0, stream>>>(u13, w2b, out, out, DIMM, HID, 8192);
}

// Round 7
// 661.190 us; speedup vs baseline: 1.3870x; 1.0673x over previous
//
#include <hip/hip_runtime.h>

#define S_LEN 4096
#define DIMM  1024
#define NH    16
#define HD    64
#define HID   4096

typedef unsigned short u16;
typedef __attribute__((ext_vector_type(8))) short bf16x8;
typedef __attribute__((ext_vector_type(4))) short short4b;
typedef __attribute__((ext_vector_type(8))) unsigned short u16x8;
typedef __attribute__((ext_vector_type(4))) float f32x4;

__device__ __forceinline__ u16 f2bf(float f) {
  unsigned u = __float_as_uint(f);
  u += 0x7fffu + ((u >> 16) & 1u);   // round-to-nearest-even
  return (u16)(u >> 16);
}
__device__ __forceinline__ float bf2f(u16 h) {
  return __uint_as_float(((unsigned)h) << 16);
}
// pack two f32 -> (bf16(hi)<<16)|bf16(lo), truncating (1 inst)
__device__ __forceinline__ unsigned pack_bf16(float hi, float lo) {
  return __builtin_amdgcn_perm(__float_as_uint(hi), __float_as_uint(lo), 0x07060302u);
}
// 2^x via v_exp_f32 (avoid glibc __exp2f macro collision)
__device__ __forceinline__ float fexp2(float x) { return __builtin_amdgcn_exp2f(x); }

// async global->LDS, 16B per lane (dest must be wave-uniform base + lane*16)
__device__ __forceinline__ void gl_lds16(const void* g, void* l) {
  __builtin_amdgcn_global_load_lds(
      (const __attribute__((address_space(1))) void*)g,
      (__attribute__((address_space(3))) void*)l, 16, 0, 0);
}

__device__ __forceinline__ f32x4 mfma16(short4b a, short4b b, f32x4 c) {
#if __has_builtin(__builtin_amdgcn_mfma_f32_16x16x16bf16_1k)
  return __builtin_amdgcn_mfma_f32_16x16x16bf16_1k(a, b, c, 0, 0, 0);
#else
  asm("v_mfma_f32_16x16x16_bf16 %0, %1, %2, %0" : "+v"(c) : "v"(a), "v"(b));
  return c;
#endif
}

// ---------------- fused prep: weight cvt + rope tables + rmsnorm#1 ----------------
// blocks 0..2047: wq/wk/wv/wo cvt; 2048..8191: w1/w3/w2 cvt; 8192..8703: rope tables;
// 8704..12799: rmsnorm(x, g_attn) -> xnb
__global__ __launch_bounds__(256) void prep_kernel(
    const float* __restrict__ wq, const float* __restrict__ wk, const float* __restrict__ wv,
    const float* __restrict__ wo, const float* __restrict__ w1, const float* __restrict__ w3,
    const float* __restrict__ w2, const float* __restrict__ x, const float* __restrict__ g_attn,
    u16* __restrict__ wqkb, u16* __restrict__ wvb, u16* __restrict__ wob,
    u16* __restrict__ w13b, u16* __restrict__ w2b, u16* __restrict__ xnb,
    float* __restrict__ cosT, float* __restrict__ sinT) {
  int b = blockIdx.x;
  int t = threadIdx.x;
  if (b < 8192) {
    const float* src;
    u16* dst;
    int i;
    if (b < 2048) {
      int which = b >> 9, lb = b & 511;
      src = which == 0 ? wq : which == 1 ? wk : which == 2 ? wv : wo;
      dst = which == 0 ? wqkb : which == 1 ? (wqkb + (1 << 20)) : which == 2 ? wvb : wob;
      i = (lb * 256 + t) * 8;
    } else {
      int b2 = b - 2048, which = b2 >> 11, lb = b2 & 2047;
      src = which == 0 ? w1 : which == 1 ? w3 : w2;
      dst = which == 0 ? w13b : which == 1 ? (w13b + (4 << 20)) : w2b;
      i = (lb * 256 + t) * 8;
    }
    float4 a = *(const float4*)(src + i);
    float4 c = *(const float4*)(src + i + 4);
    u16x8 r;
    r[0] = f2bf(a.x); r[1] = f2bf(a.y); r[2] = f2bf(a.z); r[3] = f2bf(a.w);
    r[4] = f2bf(c.x); r[5] = f2bf(c.y); r[6] = f2bf(c.z); r[7] = f2bf(c.w);
    *(u16x8*)(dst + i) = r;
  } else if (b < 8704) {
    int idx = (b - 8192) * 256 + t;  // 4096*32
    int pos = idx >> 5, i = idx & 31;
    double inv = pow(10000.0, -(double)(2 * i) / 64.0);
    double a = (double)pos * inv;
    cosT[idx] = (float)cos(a);
    sinT[idx] = (float)sin(a);
  } else {
    int row = b - 8704;
    const float4 v = *(const float4*)(x + (size_t)row * DIMM + t * 4);
    float ss = v.x * v.x + v.y * v.y + v.z * v.z + v.w * v.w;
#pragma unroll
    for (int off = 32; off > 0; off >>= 1) ss += __shfl_down(ss, off);
    __shared__ float red[4];
    if ((t & 63) == 0) red[t >> 6] = ss;
    __syncthreads();
    float tot = red[0] + red[1] + red[2] + red[3];
    float sc = rsqrtf(tot * (1.0f / DIMM) + 1e-6f);
    const float4 gv = *(const float4*)(g_attn + t * 4);
    ushort4 o;
    o.x = f2bf(v.x * sc * gv.x);
    o.y = f2bf(v.y * sc * gv.y);
    o.z = f2bf(v.z * sc * gv.z);
    o.w = f2bf(v.w * sc * gv.w);
    *(ushort4*)(xnb + (size_t)row * DIMM + t * 4) = o;
  }
}

// ---------------- RMSNorm: fp32 in -> bf16 out (for hn) ----------------
__global__ __launch_bounds__(256) void rmsnorm_kernel(const float* __restrict__ x, const float* __restrict__ g,
                                                      u16* __restrict__ out) {
  int row = blockIdx.x;
  int t = threadIdx.x;
  const float4 v = *(const float4*)(x + (size_t)row * DIMM + t * 4);
  float ss = v.x * v.x + v.y * v.y + v.z * v.z + v.w * v.w;
#pragma unroll
  for (int off = 32; off > 0; off >>= 1) ss += __shfl_down(ss, off);
  __shared__ float red[4];
  if ((t & 63) == 0) red[t >> 6] = ss;
  __syncthreads();
  float tot = red[0] + red[1] + red[2] + red[3];
  float sc = rsqrtf(tot * (1.0f / DIMM) + 1e-6f);
  const float4 gv = *(const float4*)(g + t * 4);
  ushort4 o;
  o.x = f2bf(v.x * sc * gv.x);
  o.y = f2bf(v.y * sc * gv.y);
  o.z = f2bf(v.z * sc * gv.z);
  o.w = f2bf(v.w * sc * gv.w);
  *(ushort4*)(out + (size_t)row * DIMM + t * 4) = o;
}

// ---------------- bf16 MFMA GEMM: C[M,N] = A[M,K] * B[N,K]^T ----------------
// 128x128 tile, BK=32, 4 waves 2x2, fragment-contiguous LDS, global_load_lds staging.
// lda = A row stride. OUTMODE 0: bf16. OUTMODE 1: fp32 = res + acc. OUTMODE 2: bf16 V-swizzle.
template <int OUTMODE>
__global__ __launch_bounds__(256) void gemm_kernel(const u16* __restrict__ A, const u16* __restrict__ B,
                                                   void* Cout, const float* res, int N, int K, int lda) {
  __shared__ uint4 As[512];
  __shared__ uint4 Bs[512];
  const int t = threadIdx.x;
  const int w = t >> 6, l = t & 63;
  const int bm = blockIdx.y, bn = blockIdx.x;
  const int quad = l >> 4, lc = l & 15;

  f32x4 acc[4][4];
  const f32x4 zero = {0.0f, 0.0f, 0.0f, 0.0f};
#pragma unroll
  for (int mi = 0; mi < 4; mi++)
#pragma unroll
    for (int ni = 0; ni < 4; ni++) acc[mi][ni] = zero;

  const int id0 = t, id1 = t + 256;
  const int band0 = id0 >> 6, kq0 = (id0 >> 4) & 3, row0 = id0 & 15;
  const int band1 = id1 >> 6, kq1 = (id1 >> 4) & 3, row1 = id1 & 15;
  const u16* Ap0 = A + (size_t)(bm * 128 + band0 * 16 + row0) * lda + kq0 * 8;
  const u16* Ap1 = A + (size_t)(bm * 128 + band1 * 16 + row1) * lda + kq1 * 8;
  const u16* Bp0 = B + (size_t)(bn * 128 + band0 * 16 + row0) * K + kq0 * 8;
  const u16* Bp1 = B + (size_t)(bn * 128 + band1 * 16 + row1) * K + kq1 * 8;
  const int abase = (w >> 1) * 256 + l;
  const int bbase = (w & 1) * 256 + l;

  for (int k0 = 0; k0 < K; k0 += 32) {
    gl_lds16(Ap0 + k0, &As[id0]);
    gl_lds16(Ap1 + k0, &As[id1]);
    gl_lds16(Bp0 + k0, &Bs[id0]);
    gl_lds16(Bp1 + k0, &Bs[id1]);
    __syncthreads();
    bf16x8 af[4], bfr[4];
#pragma unroll
    for (int mi = 0; mi < 4; mi++) af[mi] = *(const bf16x8*)&As[abase + mi * 64];
#pragma unroll
    for (int ni = 0; ni < 4; ni++) bfr[ni] = *(const bf16x8*)&Bs[bbase + ni * 64];
#pragma unroll
    for (int mi = 0; mi < 4; mi++)
#pragma unroll
      for (int ni = 0; ni < 4; ni++)
        acc[mi][ni] = __builtin_amdgcn_mfma_f32_16x16x32_bf16(af[mi], bfr[ni], acc[mi][ni], 0, 0, 0);
    __syncthreads();
  }

  const int rbase = bm * 128 + (w >> 1) * 64 + quad * 4;
  const int cbase = bn * 128 + (w & 1) * 64 + lc;
#pragma unroll
  for (int mi = 0; mi < 4; mi++) {
#pragma unroll
    for (int r = 0; r < 4; r++) {
      int row = rbase + mi * 16 + r;
#pragma unroll
      for (int ni = 0; ni < 4; ni++) {
        int col = cbase + ni * 16;
        if constexpr (OUTMODE == 0) {
          ((u16*)Cout)[(size_t)row * N + col] = f2bf(acc[mi][ni][r]);
        } else if constexpr (OUTMODE == 1) {
          size_t idx = (size_t)row * N + col;
          ((float*)Cout)[idx] = res[idx] + acc[mi][ni][r];
        } else {
          // V-swizzle: row = value-dim, col = key. Produces the V^T fragment image.
          int h = row >> 6, din = row & 63;
          int kb = col >> 6, k63 = col & 63;
          int off = ((h << 6) + kb) * 4096 + (((din >> 4) << 1) + (k63 >> 5)) * 512 +
                    ((((k63 >> 2) & 3) << 4) + (din & 15)) * 8 + ((k63 >> 4) & 1) * 4 + (k63 & 3);
          ((u16*)Cout)[off] = f2bf(acc[mi][ni][r]);
        }
      }
    }
  }
}

// qk buffer: [4096 rows][2048 cols]: cols 0..1023 = Q, 1024..2047 = K (both roped in place)
__global__ __launch_bounds__(256) void rope_apply_kernel(u16* __restrict__ qk,
                                                         const float* __restrict__ cosT,
                                                         const float* __restrict__ sinT) {
  int idx = blockIdx.x * 256 + threadIdx.x;  // 4096*16*32
  int pos = idx >> 9, h = (idx >> 5) & 15, i = idx & 31;
  float c = cosT[(pos << 5) + i], s = sinT[(pos << 5) + i];
  size_t base = (size_t)pos * 2048 + h * HD + 2 * i;
  float re = bf2f(qk[base]), im = bf2f(qk[base + 1]);
  qk[base] = f2bf(re * c - im * s);
  qk[base + 1] = f2bf(re * s + im * c);
  re = bf2f(qk[base + 1024]);
  im = bf2f(qk[base + 1025]);
  qk[base + 1024] = f2bf(re * c - im * s);
  qk[base + 1025] = f2bf(re * s + im * c);
}

// ---------------- Flash attention, transposed orientation, 8 waves/block ----------------
// S^T = K*Q^T per 64-key tile; exp'd S^T C-frags feed 16x16x16 PV directly.
// Block: 8 waves x 16 queries = 128 q rows, one head. Grid (32, 16). 512 threads.
__global__ __launch_bounds__(512) void attn_kernel(const u16* __restrict__ Qm, const u16* __restrict__ Km,
                                                   const u16* __restrict__ Vsw, u16* __restrict__ Om) {
  __shared__ char smem[18432];
  uint4* Ks = (uint4*)smem;             // 8KB: K tile [64 keys][64 d], A32-frag contiguous
  uint4* Vs = (uint4*)(smem + 8192);    // 8KB: V^T tile, A16-frag-pair contiguous
  const int t = threadIdx.x;
  const int w = t >> 6, l = t & 63;
  const int quad = l >> 4, lc = l & 15;
  const int hd = blockIdx.y;
  const int qrow = blockIdx.x * 128 + w * 16;

  // Q B-frags (loop-invariant, registers)
  bf16x8 qf_[2];
#pragma unroll
  for (int ch = 0; ch < 2; ch++)
    qf_[ch] = *(const bf16x8*)(Qm + (size_t)(qrow + lc) * 2048 + hd * HD + ch * 32 + quad * 8);

  const f32x4 zero = {0.0f, 0.0f, 0.0f, 0.0f};
  f32x4 Oa[4];
#pragma unroll
  for (int df = 0; df < 4; df++) Oa[df] = zero;
  float mt = -1e30f, ls = 0.0f;

  // staging: 512 threads stage the full K tile (512 uint4) and V tile (512 uint4), 1 each
  const int s0 = t >> 7, c0 = (t >> 6) & 1, kq0 = (t >> 4) & 3, row0 = t & 15;
  const u16* Kp0 = Km + (size_t)(s0 * 16 + row0) * 2048 + hd * HD + c0 * 32 + kq0 * 8;
  const u16* Vp = Vsw + (size_t)(hd * HD) * 4096 + t * 8;
  const float csc = 0.125f * 1.44269504088896f;  // 1/sqrt(64) * log2(e)

  for (int kt = 0; kt < S_LEN; kt += 64) {
    gl_lds16(Kp0 + (size_t)kt * 2048, &Ks[t]);
    gl_lds16(Vp + (size_t)(kt >> 6) * 4096, &Vs[t]);
    __syncthreads();

    // S^T = K Q^T, scaled into exp2-space
    f32x4 Sf[4];
#pragma unroll
    for (int kf = 0; kf < 4; kf++) {
      bf16x8 ka = *(const bf16x8*)&Ks[kf * 128 + l];
      bf16x8 kb2 = *(const bf16x8*)&Ks[kf * 128 + 64 + l];
      f32x4 z = __builtin_amdgcn_mfma_f32_16x16x32_bf16(ka, qf_[0], zero, 0, 0, 0);
      z = __builtin_amdgcn_mfma_f32_16x16x32_bf16(kb2, qf_[1], z, 0, 0, 0);
      Sf[kf] = z * csc;
    }

    // online softmax (keys live in regs+quads: in-reg reduce + 2 swizzles)
    float tmax = -1e30f;
#pragma unroll
    for (int kf = 0; kf < 4; kf++)
#pragma unroll
      for (int r = 0; r < 4; r++) tmax = fmaxf(tmax, Sf[kf][r]);
    tmax = fmaxf(tmax, __shfl_xor(tmax, 16));
    tmax = fmaxf(tmax, __shfl_xor(tmax, 32));
    float mnew = fmaxf(mt, tmax);
    float alpha = fexp2(mt - mnew);
    mt = mnew;
    float psum = 0.0f;
#pragma unroll
    for (int kf = 0; kf < 4; kf++)
#pragma unroll
      for (int r = 0; r < 4; r++) {
        float p = fexp2(Sf[kf][r] - mnew);
        Sf[kf][r] = p;
        psum += p;
      }
    psum += __shfl_xor(psum, 16);
    psum += __shfl_xor(psum, 32);
    ls = ls * alpha + psum;
#pragma unroll
    for (int df = 0; df < 4; df++) Oa[df] *= alpha;
    // pack exp'd S^T frags into PV B-operands (C-layout == B16-layout)
    short4b pk[4];
#pragma unroll
    for (int kf = 0; kf < 4; kf++) {
      union { short4b s4; uint2 u2; } cv;
      cv.u2.x = pack_bf16(Sf[kf][1], Sf[kf][0]);
      cv.u2.y = pack_bf16(Sf[kf][3], Sf[kf][2]);
      pk[kf] = cv.s4;
    }

    // O^T += V^T * P^T  (16x16x16 MFMAs)
#pragma unroll
    for (int df = 0; df < 4; df++)
#pragma unroll
      for (int tp = 0; tp < 2; tp++) {
        union { bf16x8 v8; short4b h[2]; } vv;
        vv.v8 = *(const bf16x8*)&Vs[(df * 2 + tp) * 64 + l];
        Oa[df] = mfma16(vv.h[0], pk[2 * tp], Oa[df]);
        Oa[df] = mfma16(vv.h[1], pk[2 * tp + 1], Oa[df]);
      }
    __syncthreads();
  }

  // epilogue: O^T frags -> LDS [128 q][64 d] (stride 72) -> coalesced global
  u16* ep = (u16*)smem;
  float invl = 1.0f / ls;
#pragma unroll
  for (int df = 0; df < 4; df++) {
    int qb = w * 16 + lc;
    int d = df * 16 + quad * 4;
    uint2 pv;
    pv.x = pack_bf16(Oa[df][1] * invl, Oa[df][0] * invl);
    pv.y = pack_bf16(Oa[df][3] * invl, Oa[df][2] * invl);
    *(uint2*)(ep + qb * 72 + d) = pv;
  }
  __syncthreads();
#pragma unroll
  for (int it = 0; it < 2; it++) {
    int qb = it * 64 + (t >> 3);
    int dp = (t & 7) * 8;
    u16x8 rowv = *(const u16x8*)(ep + qb * 72 + dp);
    *(u16x8*)(Om + (size_t)(blockIdx.x * 128 + qb) * DIMM + hd * HD + dp) = rowv;
  }
}

// ---------------- silu(u) * g on fused [4096][8192] buffer (u cols 0..4095, g cols 4096..8191) ----
__global__ __launch_bounds__(256) void silu_mul_kernel(u16* __restrict__ u13) {
  int i = (blockIdx.x * 256 + threadIdx.x) * 8;
  int r = i >> 12, c = i & 4095;
  u16* up = u13 + (size_t)r * 8192 + c;
  u16x8 uv = *(const u16x8*)up;
  u16x8 gv = *(const u16x8*)(up + 4096);
  u16x8 o;
#pragma unroll
  for (int j = 0; j < 8; j++) {
    float a = bf2f(uv[j]);
    float b = bf2f(gv[j]);
    float sv = a / (1.0f + __expf(-a));
    o[j] = f2bf(sv * b);
  }
  *(u16x8*)up = o;
}

extern "C" void kernel_launch(void* const* d_in, const int* in_sizes, int n_in,
                              void* d_out, int out_size, void* d_ws, size_t ws_size,
                              hipStream_t stream) {
  const float* x      = (const float*)d_in[0];
  const float* wq     = (const float*)d_in[1];
  const float* wk     = (const float*)d_in[2];
  const float* wv     = (const float*)d_in[3];
  const float* wo     = (const float*)d_in[4];
  const float* w1     = (const float*)d_in[5];
  const float* w2     = (const float*)d_in[6];
  const float* w3     = (const float*)d_in[7];
  const float* g_attn = (const float*)d_in[8];
  const float* g_ffn  = (const float*)d_in[9];
  float* out = (float*)d_out;
  char* ws = (char*)d_ws;
  const size_t MB = 1ull << 20;

  u16* wqkb = (u16*)(ws + 0 * MB);    // [2048][1024]: rows 0-1023 wq, 1024-2047 wk
  u16* wvb  = (u16*)(ws + 4 * MB);
  u16* wob  = (u16*)(ws + 6 * MB);
  u16* w13b = (u16*)(ws + 8 * MB);    // [8192][1024]: rows 0-4095 w1, 4096-8191 w3
  u16* w2b  = (u16*)(ws + 24 * MB);
  u16* xnb  = (u16*)(ws + 32 * MB);   // xn, later hn
  u16* qkb  = (u16*)(ws + 40 * MB);   // [4096][2048]
  u16* vswz = (u16*)(ws + 56 * MB);   // V^T fragment image, 8MB
  u16* attb = (u16*)(ws + 64 * MB);
  u16* u13  = (u16*)(ws + 40 * MB);   // [4096][8192], reuses qk/vswz/att region after o-proj
  float* cosT = (float*)(ws + 104 * MB);
  float* sinT = (float*)(ws + 104 * MB + 512 * 1024);

  // fused: all weight converts + rope tables + rmsnorm#1
  prep_kernel<<<12800, 256, 0, stream>>>(wq, wk, wv, wo, w1, w3, w2, x, g_attn,
                                         wqkb, wvb, wob, w13b, w2b, xnb, cosT, sinT);

  // QK fused: C[4096][2048]
  gemm_kernel<0><<<dim3(16, 32), 256, 0, stream>>>(xnb, wqkb, qkb, nullptr, 2048, DIMM, DIMM);
  // V^T = wv @ xn^T, stored as fragment image
  gemm_kernel<2><<<dim3(32, 8), 256, 0, stream>>>(wvb, xnb, vswz, nullptr, S_LEN, DIMM, DIMM);

  rope_apply_kernel<<<8192, 256, 0, stream>>>(qkb, cosT, sinT);

  attn_kernel<<<dim3(32, 16), 512, 0, stream>>>(qkb, qkb + 1024, vswz, attb);

  // h = x + attn @ wo^T  (h lives in d_out)
  gemm_kernel<1><<<dim3(8, 32), 256, 0, stream>>>(attb, wob, out, x, DIMM, DIMM, DIMM);

  rmsnorm_kernel<<<4096, 256, 0, stream>>>(out, g_ffn, xnb);

  // fused W1|W3: [4096][8192]
  gemm_kernel<0><<<dim3(64, 32), 256, 0, stream>>>(xnb, w13b, u13, nullptr, 8192, DIMM, DIMM);

  silu_mul_kernel<<<8192, 256, 0, stream>>>(u13);

  // out = h + ff @ w2^T  (A = u half of u13, lda = 8192; in-place residual from d_out)
  gemm_kernel<1><<<dim3(8, 32), 256, 0, stream>>>(u13, w2b, out, out, DIMM, HID, 8192);
}

// Round 8
// 612.916 us; speedup vs baseline: 1.4963x; 1.0788x over previous
//
#include <hip/hip_runtime.h>

#define S_LEN 4096
#define DIMM  1024
#define NH    16
#define HD    64
#define HID   4096

typedef unsigned short u16;
typedef __attribute__((ext_vector_type(8))) short bf16x8;
typedef __attribute__((ext_vector_type(4))) short short4b;
typedef __attribute__((ext_vector_type(8))) unsigned short u16x8;
typedef __attribute__((ext_vector_type(4))) float f32x4;

__device__ __forceinline__ u16 f2bf(float f) {
  unsigned u = __float_as_uint(f);
  u += 0x7fffu + ((u >> 16) & 1u);   // round-to-nearest-even
  return (u16)(u >> 16);
}
__device__ __forceinline__ float bf2f(u16 h) {
  return __uint_as_float(((unsigned)h) << 16);
}
// pack two f32 -> (bf16(hi)<<16)|bf16(lo), truncating (1 inst)
__device__ __forceinline__ unsigned pack_bf16(float hi, float lo) {
  return __builtin_amdgcn_perm(__float_as_uint(hi), __float_as_uint(lo), 0x07060302u);
}
// 2^x via v_exp_f32 (avoid glibc __exp2f macro collision)
__device__ __forceinline__ float fexp2(float x) { return __builtin_amdgcn_exp2f(x); }

// async global->LDS, 16B per lane (dest must be wave-uniform base + lane*16)
__device__ __forceinline__ void gl_lds16(const void* g, void* l) {
  __builtin_amdgcn_global_load_lds(
      (const __attribute__((address_space(1))) void*)g,
      (__attribute__((address_space(3))) void*)l, 16, 0, 0);
}

__device__ __forceinline__ f32x4 mfma16(short4b a, short4b b, f32x4 c) {
#if __has_builtin(__builtin_amdgcn_mfma_f32_16x16x16bf16_1k)
  return __builtin_amdgcn_mfma_f32_16x16x16bf16_1k(a, b, c, 0, 0, 0);
#else
  asm("v_mfma_f32_16x16x16_bf16 %0, %1, %2, %0" : "+v"(c) : "v"(a), "v"(b));
  return c;
#endif
}

// ---------------- fused prep: weight cvt + rope tables + rmsnorm#1 ----------------
__global__ __launch_bounds__(256) void prep_kernel(
    const float* __restrict__ wq, const float* __restrict__ wk, const float* __restrict__ wv,
    const float* __restrict__ wo, const float* __restrict__ w1, const float* __restrict__ w3,
    const float* __restrict__ w2, const float* __restrict__ x, const float* __restrict__ g_attn,
    u16* __restrict__ wqkb, u16* __restrict__ wvb, u16* __restrict__ wob,
    u16* __restrict__ w13b, u16* __restrict__ w2b, u16* __restrict__ xnb,
    float* __restrict__ cosT, float* __restrict__ sinT) {
  int b = blockIdx.x;
  int t = threadIdx.x;
  if (b < 8192) {
    const float* src;
    u16* dst;
    int i;
    if (b < 2048) {
      int which = b >> 9, lb = b & 511;
      src = which == 0 ? wq : which == 1 ? wk : which == 2 ? wv : wo;
      dst = which == 0 ? wqkb : which == 1 ? (wqkb + (1 << 20)) : which == 2 ? wvb : wob;
      i = (lb * 256 + t) * 8;
    } else {
      int b2 = b - 2048, which = b2 >> 11, lb = b2 & 2047;
      src = which == 0 ? w1 : which == 1 ? w3 : w2;
      dst = which == 0 ? w13b : which == 1 ? (w13b + (4 << 20)) : w2b;
      i = (lb * 256 + t) * 8;
    }
    float4 a = *(const float4*)(src + i);
    float4 c = *(const float4*)(src + i + 4);
    u16x8 r;
    r[0] = f2bf(a.x); r[1] = f2bf(a.y); r[2] = f2bf(a.z); r[3] = f2bf(a.w);
    r[4] = f2bf(c.x); r[5] = f2bf(c.y); r[6] = f2bf(c.z); r[7] = f2bf(c.w);
    *(u16x8*)(dst + i) = r;
  } else if (b < 8704) {
    int idx = (b - 8192) * 256 + t;  // 4096*32
    int pos = idx >> 5, i = idx & 31;
    double inv = pow(10000.0, -(double)(2 * i) / 64.0);
    double a = (double)pos * inv;
    cosT[idx] = (float)cos(a);
    sinT[idx] = (float)sin(a);
  } else {
    int row = b - 8704;
    const float4 v = *(const float4*)(x + (size_t)row * DIMM + t * 4);
    float ss = v.x * v.x + v.y * v.y + v.z * v.z + v.w * v.w;
#pragma unroll
    for (int off = 32; off > 0; off >>= 1) ss += __shfl_down(ss, off);
    __shared__ float red[4];
    if ((t & 63) == 0) red[t >> 6] = ss;
    __syncthreads();
    float tot = red[0] + red[1] + red[2] + red[3];
    float sc = rsqrtf(tot * (1.0f / DIMM) + 1e-6f);
    const float4 gv = *(const float4*)(g_attn + t * 4);
    ushort4 o;
    o.x = f2bf(v.x * sc * gv.x);
    o.y = f2bf(v.y * sc * gv.y);
    o.z = f2bf(v.z * sc * gv.z);
    o.w = f2bf(v.w * sc * gv.w);
    *(ushort4*)(xnb + (size_t)row * DIMM + t * 4) = o;
  }
}

// ---------------- RMSNorm: fp32 in -> bf16 out (for hn) ----------------
__global__ __launch_bounds__(256) void rmsnorm_kernel(const float* __restrict__ x, const float* __restrict__ g,
                                                      u16* __restrict__ out) {
  int row = blockIdx.x;
  int t = threadIdx.x;
  const float4 v = *(const float4*)(x + (size_t)row * DIMM + t * 4);
  float ss = v.x * v.x + v.y * v.y + v.z * v.z + v.w * v.w;
#pragma unroll
  for (int off = 32; off > 0; off >>= 1) ss += __shfl_down(ss, off);
  __shared__ float red[4];
  if ((t & 63) == 0) red[t >> 6] = ss;
  __syncthreads();
  float tot = red[0] + red[1] + red[2] + red[3];
  float sc = rsqrtf(tot * (1.0f / DIMM) + 1e-6f);
  const float4 gv = *(const float4*)(g + t * 4);
  ushort4 o;
  o.x = f2bf(v.x * sc * gv.x);
  o.y = f2bf(v.y * sc * gv.y);
  o.z = f2bf(v.z * sc * gv.z);
  o.w = f2bf(v.w * sc * gv.w);
  *(ushort4*)(out + (size_t)row * DIMM + t * 4) = o;
}

// ---------------- bf16 MFMA GEMM: C[M,N] = A[M,K] * B[N,K]^T ----------------
// 128x128 tile, BK=32, 8 waves (4 M-groups x 2 N-halves), each wave 32x64 (2x4 frags).
// Fragment-contiguous LDS, global_load_lds staging. lda = A row stride.
// OUTMODE 0: bf16. OUTMODE 1: fp32 = res + acc. OUTMODE 2: bf16 V-swizzle.
// OUTMODE 3: bf16 with RoPE applied (QK projection; cosT/sinT tables).
template <int OUTMODE>
__global__ __launch_bounds__(512) void gemm_kernel(const u16* __restrict__ A, const u16* __restrict__ B,
                                                   void* Cout, const float* res, int N, int K, int lda,
                                                   const float* cosT, const float* sinT) {
  __shared__ uint4 As[512];
  __shared__ uint4 Bs[512];
  const int t = threadIdx.x;
  const int w = t >> 6, l = t & 63;
  const int wm = w >> 1, wn = w & 1;
  const int bm = blockIdx.y, bn = blockIdx.x;
  const int quad = l >> 4, lc = l & 15;

  f32x4 acc[2][4];
  const f32x4 zero = {0.0f, 0.0f, 0.0f, 0.0f};
#pragma unroll
  for (int mi = 0; mi < 2; mi++)
#pragma unroll
    for (int ni = 0; ni < 4; ni++) acc[mi][ni] = zero;

  // staging: thread t stages As[t] and Bs[t] (t = band*64 + kq*16 + row)
  const int band0 = t >> 6, kq0 = (t >> 4) & 3, row0 = t & 15;
  const u16* Ap0 = A + (size_t)(bm * 128 + band0 * 16 + row0) * lda + kq0 * 8;
  const u16* Bp0 = B + (size_t)(bn * 128 + band0 * 16 + row0) * K + kq0 * 8;
  const int abase = wm * 128 + l;   // (wm*2+mi)*64 + l
  const int bbase = wn * 256 + l;   // (wn*4+ni)*64 + l

  for (int k0 = 0; k0 < K; k0 += 32) {
    gl_lds16(Ap0 + k0, &As[t]);
    gl_lds16(Bp0 + k0, &Bs[t]);
    __syncthreads();
    bf16x8 af[2], bfr[4];
#pragma unroll
    for (int mi = 0; mi < 2; mi++) af[mi] = *(const bf16x8*)&As[abase + mi * 64];
#pragma unroll
    for (int ni = 0; ni < 4; ni++) bfr[ni] = *(const bf16x8*)&Bs[bbase + ni * 64];
#pragma unroll
    for (int mi = 0; mi < 2; mi++)
#pragma unroll
      for (int ni = 0; ni < 4; ni++)
        acc[mi][ni] = __builtin_amdgcn_mfma_f32_16x16x32_bf16(af[mi], bfr[ni], acc[mi][ni], 0, 0, 0);
    __syncthreads();
  }

  const int rbase = bm * 128 + wm * 32 + quad * 4;
  const int cbase = bn * 128 + wn * 64 + lc;
#pragma unroll
  for (int mi = 0; mi < 2; mi++) {
#pragma unroll
    for (int r = 0; r < 4; r++) {
      int row = rbase + mi * 16 + r;
#pragma unroll
      for (int ni = 0; ni < 4; ni++) {
        int col = cbase + ni * 16;
        if constexpr (OUTMODE == 0) {
          ((u16*)Cout)[(size_t)row * N + col] = f2bf(acc[mi][ni][r]);
        } else if constexpr (OUTMODE == 1) {
          size_t idx = (size_t)row * N + col;
          ((float*)Cout)[idx] = res[idx] + acc[mi][ni][r];
        } else if constexpr (OUTMODE == 2) {
          // V-swizzle: row = value-dim, col = key. Produces the V^T fragment image.
          int h = row >> 6, din = row & 63;
          int kb = col >> 6, k63 = col & 63;
          int off = ((h << 6) + kb) * 4096 + (((din >> 4) << 1) + (k63 >> 5)) * 512 +
                    ((((k63 >> 2) & 3) << 4) + (din & 15)) * 8 + ((k63 >> 4) & 1) * 4 + (k63 & 3);
          ((u16*)Cout)[off] = f2bf(acc[mi][ni][r]);
        } else {
          // RoPE fused: col parity == lane parity; partner value via shfl_xor(1).
          float v = acc[mi][ni][r];
          float pv = __shfl_xor(v, 1);
          int i = ((ni * 16 + lc) & 63) >> 1;
          float c = cosT[(row << 5) + i], s = sinT[(row << 5) + i];
          float o = (lc & 1) ? (pv * s + v * c) : (v * c - pv * s);
          ((u16*)Cout)[(size_t)row * N + col] = f2bf(o);
        }
      }
    }
  }
}

// ---------------- Flash attention, transposed orientation, 8 waves/block ----------------
// S^T = K*Q^T per 64-key tile; exp'd S^T C-frags feed 16x16x16 PV directly.
// Block: 8 waves x 16 queries = 128 q rows, one head. Grid (32, 16). 512 threads.
__global__ __launch_bounds__(512) void attn_kernel(const u16* __restrict__ Qm, const u16* __restrict__ Km,
                                                   const u16* __restrict__ Vsw, u16* __restrict__ Om) {
  __shared__ char smem[18432];
  uint4* Ks = (uint4*)smem;             // 8KB: K tile [64 keys][64 d], A32-frag contiguous
  uint4* Vs = (uint4*)(smem + 8192);    // 8KB: V^T tile, A16-frag-pair contiguous
  const int t = threadIdx.x;
  const int w = t >> 6, l = t & 63;
  const int quad = l >> 4, lc = l & 15;
  const int hd = blockIdx.y;
  const int qrow = blockIdx.x * 128 + w * 16;

  // Q B-frags (loop-invariant, registers)
  bf16x8 qf_[2];
#pragma unroll
  for (int ch = 0; ch < 2; ch++)
    qf_[ch] = *(const bf16x8*)(Qm + (size_t)(qrow + lc) * 2048 + hd * HD + ch * 32 + quad * 8);

  const f32x4 zero = {0.0f, 0.0f, 0.0f, 0.0f};
  f32x4 Oa[4];
#pragma unroll
  for (int df = 0; df < 4; df++) Oa[df] = zero;
  float mt = -1e30f, ls = 0.0f;

  // staging: 512 threads stage the full K tile (512 uint4) and V tile (512 uint4), 1 each
  const int s0 = t >> 7, c0 = (t >> 6) & 1, kq0 = (t >> 4) & 3, row0 = t & 15;
  const u16* Kp0 = Km + (size_t)(s0 * 16 + row0) * 2048 + hd * HD + c0 * 32 + kq0 * 8;
  const u16* Vp = Vsw + (size_t)(hd * HD) * 4096 + t * 8;
  const float csc = 0.125f * 1.44269504088896f;  // 1/sqrt(64) * log2(e)

  for (int kt = 0; kt < S_LEN; kt += 64) {
    gl_lds16(Kp0 + (size_t)kt * 2048, &Ks[t]);
    gl_lds16(Vp + (size_t)(kt >> 6) * 4096, &Vs[t]);
    __syncthreads();

    // S^T = K Q^T, scaled into exp2-space
    f32x4 Sf[4];
#pragma unroll
    for (int kf = 0; kf < 4; kf++) {
      bf16x8 ka = *(const bf16x8*)&Ks[kf * 128 + l];
      bf16x8 kb2 = *(const bf16x8*)&Ks[kf * 128 + 64 + l];
      f32x4 z = __builtin_amdgcn_mfma_f32_16x16x32_bf16(ka, qf_[0], zero, 0, 0, 0);
      z = __builtin_amdgcn_mfma_f32_16x16x32_bf16(kb2, qf_[1], z, 0, 0, 0);
      Sf[kf] = z * csc;
    }

    // online softmax (keys live in regs+quads: in-reg reduce + 2 swizzles)
    float tmax = -1e30f;
#pragma unroll
    for (int kf = 0; kf < 4; kf++)
#pragma unroll
      for (int r = 0; r < 4; r++) tmax = fmaxf(tmax, Sf[kf][r]);
    tmax = fmaxf(tmax, __shfl_xor(tmax, 16));
    tmax = fmaxf(tmax, __shfl_xor(tmax, 32));
    float mnew = fmaxf(mt, tmax);
    float alpha = fexp2(mt - mnew);
    mt = mnew;
    float psum = 0.0f;
#pragma unroll
    for (int kf = 0; kf < 4; kf++)
#pragma unroll
      for (int r = 0; r < 4; r++) {
        float p = fexp2(Sf[kf][r] - mnew);
        Sf[kf][r] = p;
        psum += p;
      }
    psum += __shfl_xor(psum, 16);
    psum += __shfl_xor(psum, 32);
    ls = ls * alpha + psum;
#pragma unroll
    for (int df = 0; df < 4; df++) Oa[df] *= alpha;
    // pack exp'd S^T frags into PV B-operands (C-layout == B16-layout)
    short4b pk[4];
#pragma unroll
    for (int kf = 0; kf < 4; kf++) {
      union { short4b s4; uint2 u2; } cv;
      cv.u2.x = pack_bf16(Sf[kf][1], Sf[kf][0]);
      cv.u2.y = pack_bf16(Sf[kf][3], Sf[kf][2]);
      pk[kf] = cv.s4;
    }

    // O^T += V^T * P^T  (16x16x16 MFMAs)
#pragma unroll
    for (int df = 0; df < 4; df++)
#pragma unroll
      for (int tp = 0; tp < 2; tp++) {
        union { bf16x8 v8; short4b h[2]; } vv;
        vv.v8 = *(const bf16x8*)&Vs[(df * 2 + tp) * 64 + l];
        Oa[df] = mfma16(vv.h[0], pk[2 * tp], Oa[df]);
        Oa[df] = mfma16(vv.h[1], pk[2 * tp + 1], Oa[df]);
      }
    __syncthreads();
  }

  // epilogue: O^T frags -> LDS [128 q][64 d] (stride 72) -> coalesced global
  u16* ep = (u16*)smem;
  float invl = 1.0f / ls;
#pragma unroll
  for (int df = 0; df < 4; df++) {
    int qb = w * 16 + lc;
    int d = df * 16 + quad * 4;
    uint2 pv;
    pv.x = pack_bf16(Oa[df][1] * invl, Oa[df][0] * invl);
    pv.y = pack_bf16(Oa[df][3] * invl, Oa[df][2] * invl);
    *(uint2*)(ep + qb * 72 + d) = pv;
  }
  __syncthreads();
#pragma unroll
  for (int it = 0; it < 2; it++) {
    int qb = it * 64 + (t >> 3);
    int dp = (t & 7) * 8;
    u16x8 rowv = *(const u16x8*)(ep + qb * 72 + dp);
    *(u16x8*)(Om + (size_t)(blockIdx.x * 128 + qb) * DIMM + hd * HD + dp) = rowv;
  }
}

// ---------------- silu(u) * g on fused [4096][8192] buffer (u cols 0..4095, g cols 4096..8191) ----
__global__ __launch_bounds__(256) void silu_mul_kernel(u16* __restrict__ u13) {
  int i = (blockIdx.x * 256 + threadIdx.x) * 8;
  int r = i >> 12, c = i & 4095;
  u16* up = u13 + (size_t)r * 8192 + c;
  u16x8 uv = *(const u16x8*)up;
  u16x8 gv = *(const u16x8*)(up + 4096);
  u16x8 o;
#pragma unroll
  for (int j = 0; j < 8; j++) {
    float a = bf2f(uv[j]);
    float b = bf2f(gv[j]);
    float sv = a / (1.0f + __expf(-a));
    o[j] = f2bf(sv * b);
  }
  *(u16x8*)up = o;
}

extern "C" void kernel_launch(void* const* d_in, const int* in_sizes, int n_in,
                              void* d_out, int out_size, void* d_ws, size_t ws_size,
                              hipStream_t stream) {
  const float* x      = (const float*)d_in[0];
  const float* wq     = (const float*)d_in[1];
  const float* wk     = (const float*)d_in[2];
  const float* wv     = (const float*)d_in[3];
  const float* wo     = (const float*)d_in[4];
  const float* w1     = (const float*)d_in[5];
  const float* w2     = (const float*)d_in[6];
  const float* w3     = (const float*)d_in[7];
  const float* g_attn = (const float*)d_in[8];
  const float* g_ffn  = (const float*)d_in[9];
  float* out = (float*)d_out;
  char* ws = (char*)d_ws;
  const size_t MB = 1ull << 20;

  u16* wqkb = (u16*)(ws + 0 * MB);    // [2048][1024]: rows 0-1023 wq, 1024-2047 wk
  u16* wvb  = (u16*)(ws + 4 * MB);
  u16* wob  = (u16*)(ws + 6 * MB);
  u16* w13b = (u16*)(ws + 8 * MB);    // [8192][1024]: rows 0-4095 w1, 4096-8191 w3
  u16* w2b  = (u16*)(ws + 24 * MB);
  u16* xnb  = (u16*)(ws + 32 * MB);   // xn, later hn
  u16* qkb  = (u16*)(ws + 40 * MB);   // [4096][2048]
  u16* vswz = (u16*)(ws + 56 * MB);   // V^T fragment image, 8MB
  u16* attb = (u16*)(ws + 64 * MB);
  u16* u13  = (u16*)(ws + 40 * MB);   // [4096][8192], reuses qk/vswz/att region after o-proj
  float* cosT = (float*)(ws + 104 * MB);
  float* sinT = (float*)(ws + 104 * MB + 512 * 1024);

  // fused: all weight converts + rope tables + rmsnorm#1
  prep_kernel<<<12800, 256, 0, stream>>>(wq, wk, wv, wo, w1, w3, w2, x, g_attn,
                                         wqkb, wvb, wob, w13b, w2b, xnb, cosT, sinT);

  // QK fused with RoPE epilogue: C[4096][2048]
  gemm_kernel<3><<<dim3(16, 32), 512, 0, stream>>>(xnb, wqkb, qkb, nullptr, 2048, DIMM, DIMM, cosT, sinT);
  // V^T = wv @ xn^T, stored as fragment image
  gemm_kernel<2><<<dim3(32, 8), 512, 0, stream>>>(wvb, xnb, vswz, nullptr, S_LEN, DIMM, DIMM, nullptr, nullptr);

  attn_kernel<<<dim3(32, 16), 512, 0, stream>>>(qkb, qkb + 1024, vswz, attb);

  // h = x + attn @ wo^T  (h lives in d_out)
  gemm_kernel<1><<<dim3(8, 32), 512, 0, stream>>>(attb, wob, out, x, DIMM, DIMM, DIMM, nullptr, nullptr);

  rmsnorm_kernel<<<4096, 256, 0, stream>>>(out, g_ffn, xnb);

  // fused W1|W3: [4096][8192]
  gemm_kernel<0><<<dim3(64, 32), 512, 0, stream>>>(xnb, w13b, u13, nullptr, 8192, DIMM, DIMM, nullptr, nullptr);

  silu_mul_kernel<<<8192, 256, 0, stream>>>(u13);

  // out = h + ff @ w2^T  (A = u half of u13, lda = 8192; in-place residual from d_out)
  gemm_kernel<1><<<dim3(8, 32), 512, 0, stream>>>(u13, w2b, out, out, DIMM, HID, 8192, nullptr, nullptr);
}